// Round 1
// baseline (2492.564 us; speedup 1.0000x reference)
//
#include <hip/hip_runtime.h>
#include <math.h>

typedef unsigned short ushort_t;
typedef __bf16 bf16x8 __attribute__((ext_vector_type(8)));
typedef float f32x4 __attribute__((ext_vector_type(4)));

#define SEQ 2048
#define DMODEL 2048
#define NBATCH 2
#define NHEAD 16
#define HDIM 128
#define FFDIM 8192
#define QKVN 2304   // 2048 (Q) + 128 (K) + 128 (V)

typedef __attribute__((address_space(1))) void as1_void;
typedef __attribute__((address_space(3))) void as3_void;

__device__ __forceinline__ void async_cp16(const void* g, void* l) {
  __builtin_amdgcn_global_load_lds((as1_void*)(void*)g, (as3_void*)l, 16, 0, 0);
}

__device__ __forceinline__ ushort_t f2bf(float f) {
  unsigned u = __float_as_uint(f);
  u += 0x7fff + ((u >> 16) & 1);   // round-to-nearest-even
  return (ushort_t)(u >> 16);
}

// ---------------- LayerNorm: f32 in -> bf16 out -------------------------
__global__ __launch_bounds__(256) void ln_kernel(const float* __restrict__ x,
    const float* __restrict__ gamma, const float* __restrict__ beta,
    ushort_t* __restrict__ out) {
  int row = blockIdx.x;
  int tid = threadIdx.x;
  const float4* xr = (const float4*)(x + (size_t)row * DMODEL);
  float4 a = xr[tid];
  float4 b = xr[256 + tid];
  float s  = a.x + a.y + a.z + a.w + b.x + b.y + b.z + b.w;
  float ss = a.x*a.x + a.y*a.y + a.z*a.z + a.w*a.w
           + b.x*b.x + b.y*b.y + b.z*b.z + b.w*b.w;
  for (int off = 1; off < 64; off <<= 1) {
    s  += __shfl_xor(s,  off, 64);
    ss += __shfl_xor(ss, off, 64);
  }
  __shared__ float red[8];
  int wave = tid >> 6, lane = tid & 63;
  if (lane == 0) { red[wave] = s; red[4 + wave] = ss; }
  __syncthreads();
  s  = red[0] + red[1] + red[2] + red[3];
  ss = red[4] + red[5] + red[6] + red[7];
  float mean = s * (1.0f / DMODEL);
  float var  = ss * (1.0f / DMODEL) - mean * mean;
  float rs   = rsqrtf(var + 1e-5f);
  const float4* g4 = (const float4*)gamma;
  const float4* b4 = (const float4*)beta;
  float4 g0 = g4[tid], g1 = g4[256 + tid];
  float4 e0 = b4[tid], e1 = b4[256 + tid];
  ushort_t* o = out + (size_t)row * DMODEL;
  ushort4 p0, p1;
  p0.x = f2bf((a.x - mean) * rs * g0.x + e0.x);
  p0.y = f2bf((a.y - mean) * rs * g0.y + e0.y);
  p0.z = f2bf((a.z - mean) * rs * g0.z + e0.z);
  p0.w = f2bf((a.w - mean) * rs * g0.w + e0.w);
  p1.x = f2bf((b.x - mean) * rs * g1.x + e1.x);
  p1.y = f2bf((b.y - mean) * rs * g1.y + e1.y);
  p1.z = f2bf((b.z - mean) * rs * g1.z + e1.z);
  p1.w = f2bf((b.w - mean) * rs * g1.w + e1.w);
  ((ushort4*)o)[tid]       = p0;
  ((ushort4*)o)[256 + tid] = p1;
}

// ------------- transpose + f32->bf16: src[Ks][Ns] -> dst[Ns][Ks] --------
__global__ __launch_bounds__(256) void transpose_convert(
    const float* __restrict__ src, ushort_t* __restrict__ dst, int Ks, int Ns) {
  __shared__ float tile[32][33];
  int nb = blockIdx.x * 32, kb = blockIdx.y * 32;
  int tx = threadIdx.x, ty = threadIdx.y;   // (32,8)
  for (int i = 0; i < 4; i++) {
    int k = kb + ty * 4 + i;
    tile[ty * 4 + i][tx] = src[(size_t)k * Ns + nb + tx];
  }
  __syncthreads();
  for (int i = 0; i < 4; i++) {
    int n = nb + ty * 4 + i;
    dst[(size_t)n * Ks + kb + tx] = f2bf(tile[tx][ty * 4 + i]);
  }
}

// ------------- V slice of qkv -> transposed vt[b][d][s] (bf16) ----------
__global__ __launch_bounds__(256) void transpose_v(
    const ushort_t* __restrict__ qkv, ushort_t* __restrict__ vt) {
  __shared__ ushort_t tile[32][33];
  int sb = blockIdx.x * 32, db = blockIdx.y * 32, b = blockIdx.z;
  int tx = threadIdx.x, ty = threadIdx.y;
  for (int i = 0; i < 4; i++) {
    int s = sb + ty * 4 + i;
    tile[ty * 4 + i][tx] = qkv[((size_t)(b * SEQ + s)) * QKVN + 2176 + db + tx];
  }
  __syncthreads();
  for (int i = 0; i < 4; i++) {
    int d = db + ty * 4 + i;
    vt[((size_t)(b * HDIM + d)) * SEQ + sb + tx] = tile[tx][ty * 4 + i];
  }
}

// ------------- concat q/k/v biases into one [2304] vector ---------------
__global__ void concat_bias(const float* __restrict__ qb, const float* __restrict__ kb,
                            const float* __restrict__ vb, float* __restrict__ dst) {
  int i = blockIdx.x * 256 + threadIdx.x;
  if (i < 2048) dst[i] = qb[i];
  else if (i < 2176) dst[i] = kb[i - 2048];
  else if (i < 2304) dst[i] = vb[i - 2176];
}

// ------------- GEMM: C[M,N] = A[M,K] * Bt[N,K]^T  (+bias/epilogue) ------
// MODE 0: bf16 out = acc + bias ; MODE 1: f32 out = resid + acc + bias ;
// MODE 2: bf16 out = gelu(acc + bias)
// 256x256 tile, 512 threads (8 waves, 2x4), BK=32, double-buffered LDS with
// ONE barrier per K-iter. 256^2 tiles halve per-FLOP panel traffic vs 128^2
// (issued bytes scale as 1/BM + 1/BN), and the XCD-chunked 1-D swizzle keeps
// each XCD's blocks on consecutive bn of the SAME bm so the A-panel stays
// resident in that XCD's private 4 MB L2 instead of re-streaming from LLC/HBM.
// Requires gridDim.x % 8 == 0 (all four call sites: 144/128/512/128).
template <int MODE>
__global__ __launch_bounds__(512) void gemm_bt(const ushort_t* __restrict__ A,
    const ushort_t* __restrict__ Bt, void* __restrict__ Cv,
    const float* __restrict__ bias, const float* __restrict__ resid,
    int N, int K, int GN) {
  __shared__ ushort_t sA[2][256 * 32];
  __shared__ ushort_t sB[2][256 * 32];
  int nwg = gridDim.x;
  int wg  = blockIdx.x;
  int swz = (wg & 7) * (nwg >> 3) + (wg >> 3);   // XCD-chunked swizzle (T1)
  int bm = swz / GN, bn = swz % GN;
  int tid = threadIdx.x, wave = tid >> 6, lane = tid & 63;
  int quad = lane >> 4, l16 = lane & 15;
  int wm = wave >> 2, wn = wave & 3;             // 2 (M) x 4 (N) waves
  f32x4 acc[8][4];
  for (int i = 0; i < 8; i++)
    for (int j = 0; j < 4; j++) { f32x4 z = {0.f, 0.f, 0.f, 0.f}; acc[i][j] = z; }
  const ushort_t* Ab = A  + (size_t)(bm * 256) * K;
  const ushort_t* Bb = Bt + (size_t)(bn * 256) * K;
  // 256x32 bf16 tile = 1024 16B chunks; wave w stages chunks [w*128, w*128+128)
  int cb = wave * 128;
  int c0 = cb + lane;
  size_t arow  = (size_t)(c0 >> 2) * K + (c0 & 3) * 8;
  size_t arow1 = (size_t)((c0 + 64) >> 2) * K + ((c0 + 64) & 3) * 8;
  int nk = K >> 5;
  // prefetch tile 0 into buffer 0
  async_cp16(Ab + arow,  &sA[0][cb * 8]);
  async_cp16(Ab + arow1, &sA[0][(cb + 64) * 8]);
  async_cp16(Bb + arow,  &sB[0][cb * 8]);
  async_cp16(Bb + arow1, &sB[0][(cb + 64) * 8]);
  for (int ki = 0; ki < nk; ki++) {
    int cur = ki & 1;
    __syncthreads();   // drains prefetch into `cur`; makes buf `cur^1` WAR-safe
    if (ki + 1 < nk) {
      int k0 = (ki + 1) << 5;
      async_cp16(Ab + arow  + k0, &sA[cur ^ 1][cb * 8]);
      async_cp16(Ab + arow1 + k0, &sA[cur ^ 1][(cb + 64) * 8]);
      async_cp16(Bb + arow  + k0, &sB[cur ^ 1][cb * 8]);
      async_cp16(Bb + arow1 + k0, &sB[cur ^ 1][(cb + 64) * 8]);
    }
    bf16x8 af[8], bf[4];
    for (int i = 0; i < 8; i++)
      af[i] = *(const bf16x8*)(&sA[cur][(wm * 128 + i * 16 + l16) * 32 + quad * 8]);
    for (int j = 0; j < 4; j++)
      bf[j] = *(const bf16x8*)(&sB[cur][(wn * 64 + j * 16 + l16) * 32 + quad * 8]);
    for (int i = 0; i < 8; i++)
      for (int j = 0; j < 4; j++)
        acc[i][j] = __builtin_amdgcn_mfma_f32_16x16x32_bf16(af[i], bf[j], acc[i][j], 0, 0, 0);
  }
  for (int i = 0; i < 8; i++) {
    for (int r = 0; r < 4; r++) {
      size_t row = (size_t)(bm * 256 + wm * 128 + i * 16 + quad * 4 + r);
      for (int j = 0; j < 4; j++) {
        int col = bn * 256 + wn * 64 + j * 16 + l16;
        float v = acc[i][j][r] + bias[col];
        size_t idx = row * (size_t)N + col;
        if (MODE == 0) {
          ((ushort_t*)Cv)[idx] = f2bf(v);
        } else if (MODE == 1) {
          ((float*)Cv)[idx] = resid[idx] + v;
        } else {
          float g = 0.5f * v * (1.0f + erff(v * 0.70710678118654752f));
          ((ushort_t*)Cv)[idx] = f2bf(g);
        }
      }
    }
  }
}

// ------------- Flash attention (causal, MQA) ----------------------------
// grid (S/64, H, B), block 256 = 4 waves; wave owns 16 q-rows.
__global__ __launch_bounds__(256) void flash_kernel(const ushort_t* __restrict__ qkv,
    const ushort_t* __restrict__ vt, ushort_t* __restrict__ obuf) {
  __shared__ ushort_t sK[64 * 128];    // K tile  [64 keys][128 d]
  __shared__ ushort_t sVT[128 * 64];   // V^T tile [128 d][64 keys]
  __shared__ ushort_t sP[4][16 * 64];  // per-wave P relayout buffer
  int qt = blockIdx.x, h = blockIdx.y, b = blockIdx.z;
  int tid = threadIdx.x, wave = tid >> 6, lane = tid & 63;
  int quad = lane >> 4, l16 = lane & 15;
  int qb = qt * 64 + wave * 16;
  size_t batch_off = (size_t)b * SEQ * QKVN;

  bf16x8 aq[4];
  {
    const ushort_t* qp = qkv + batch_off + (size_t)(qb + l16) * QKVN + h * HDIM + quad * 8;
    for (int c = 0; c < 4; c++) aq[c] = *(const bf16x8*)(qp + c * 32);
  }
  f32x4 oacc[8];
  for (int i = 0; i < 8; i++) { f32x4 z = {0.f, 0.f, 0.f, 0.f}; oacc[i] = z; }
  float m_i[4], l_i[4];
  for (int r = 0; r < 4; r++) { m_i[r] = -1e30f; l_i[r] = 0.f; }
  const float scale = 0.08838834764831845f;  // 1/sqrt(128)

  for (int kt = 0; kt <= qt; kt++) {
    __syncthreads();   // previous iteration done with sK/sVT
    for (int t = 0; t < 4; t++) {
      int cb = wave * 256 + t * 64;
      int c  = cb + lane;
      async_cp16(qkv + batch_off + (size_t)(kt * 64 + (c >> 4)) * QKVN + 2048 + (c & 15) * 8,
                 &sK[cb * 8]);
      async_cp16(vt + ((size_t)(b * HDIM + (c >> 3))) * SEQ + kt * 64 + (c & 7) * 8,
                 &sVT[cb * 8]);
    }
    __syncthreads();   // staged (compiler drains vmcnt before barrier)

    // Q K^T
    f32x4 sc[4];
    for (int j = 0; j < 4; j++) {
      f32x4 z = {0.f, 0.f, 0.f, 0.f};
      for (int c = 0; c < 4; c++) {
        bf16x8 bk = *(const bf16x8*)(&sK[(j * 16 + l16) * 128 + c * 32 + quad * 8]);
        z = __builtin_amdgcn_mfma_f32_16x16x32_bf16(aq[c], bk, z, 0, 0, 0);
      }
      sc[j] = z;
    }
    // scale + causal mask + online softmax
    float rmax[4] = {-1e30f, -1e30f, -1e30f, -1e30f};
    for (int j = 0; j < 4; j++) {
      int col = kt * 64 + j * 16 + l16;
      for (int r = 0; r < 4; r++) {
        int rowg = qb + quad * 4 + r;
        float v = (col <= rowg) ? sc[j][r] * scale : -1e30f;
        sc[j][r] = v;
        rmax[r] = fmaxf(rmax[r], v);
      }
    }
    for (int off = 1; off < 16; off <<= 1)
      for (int r = 0; r < 4; r++) rmax[r] = fmaxf(rmax[r], __shfl_xor(rmax[r], off, 64));
    float alpha[4], psum[4];
    for (int r = 0; r < 4; r++) {
      float mn = fmaxf(m_i[r], rmax[r]);
      alpha[r] = __expf(m_i[r] - mn);
      m_i[r] = mn;
      psum[r] = 0.f;
    }
    for (int j = 0; j < 4; j++)
      for (int r = 0; r < 4; r++) {
        float p = __expf(sc[j][r] - m_i[r]);
        sc[j][r] = p;
        psum[r] += p;
      }
    for (int off = 1; off < 16; off <<= 1)
      for (int r = 0; r < 4; r++) psum[r] += __shfl_xor(psum[r], off, 64);
    for (int r = 0; r < 4; r++) l_i[r] = l_i[r] * alpha[r] + psum[r];
    for (int i = 0; i < 8; i++)
      for (int r = 0; r < 4; r++) oacc[i][r] *= alpha[r];

    // P: C-layout -> A-layout via per-wave LDS roundtrip (sP is per-wave,
    // so a full barrier is unnecessary -- lgkmcnt(0) orders the same-wave
    // ds_write -> ds_read RAW)
    for (int j = 0; j < 4; j++)
      for (int r = 0; r < 4; r++)
        sP[wave][(quad * 4 + r) * 64 + j * 16 + l16] = f2bf(sc[j][r]);
    asm volatile("s_waitcnt lgkmcnt(0)" ::: "memory");
    bf16x8 pa[2];
    for (int c = 0; c < 2; c++)
      pa[c] = *(const bf16x8*)(&sP[wave][l16 * 64 + c * 32 + quad * 8]);
    // P V
    for (int ds = 0; ds < 8; ds++)
      for (int c = 0; c < 2; c++) {
        bf16x8 vb = *(const bf16x8*)(&sVT[(ds * 16 + l16) * 64 + c * 32 + quad * 8]);
        oacc[ds] = __builtin_amdgcn_mfma_f32_16x16x32_bf16(pa[c], vb, oacc[ds], 0, 0, 0);
      }
  }
  for (int r = 0; r < 4; r++) {
    float inv = 1.0f / l_i[r];
    size_t rowo = ((size_t)(b * SEQ + qb + quad * 4 + r)) * DMODEL + h * HDIM;
    for (int ds = 0; ds < 8; ds++)
      obuf[rowo + ds * 16 + l16] = f2bf(oacc[ds][r] * inv);
  }
}

// ------------------------------------------------------------------------
extern "C" void kernel_launch(void* const* d_in, const int* in_sizes, int n_in,
                              void* d_out, int out_size, void* d_ws, size_t ws_size,
                              hipStream_t stream) {
  const float* x     = (const float*)d_in[0];
  const float* wq_k  = (const float*)d_in[2];
  const float* wq_b  = (const float*)d_in[3];
  const float* wk_k  = (const float*)d_in[4];
  const float* wk_b  = (const float*)d_in[5];
  const float* wv_k  = (const float*)d_in[6];
  const float* wv_b  = (const float*)d_in[7];
  const float* wo_k  = (const float*)d_in[8];
  const float* wo_b  = (const float*)d_in[9];
  const float* w1_k  = (const float*)d_in[10];
  const float* w1_b  = (const float*)d_in[11];
  const float* w2_k  = (const float*)d_in[12];
  const float* w2_b  = (const float*)d_in[13];
  const float* ln1_s = (const float*)d_in[14];
  const float* ln1_b = (const float*)d_in[15];
  const float* ln2_s = (const float*)d_in[16];
  const float* ln2_b = (const float*)d_in[17];

  // workspace layout (bytes, all 256-aligned); total ~188 MB
  char* ws = (char*)d_ws;
  float*    xres = (float*)(ws + 0);                //  33.55 MB f32 [4096][2048]
  ushort_t* hbuf = (ushort_t*)(ws + 33554432);      //  16.78 MB bf16 [4096][2048]
  ushort_t* wt   = (ushort_t*)(ws + 50331648);      //  33.55 MB bf16 weight scratch
  ushort_t* qkv  = (ushort_t*)(ws + 83886080);      //  18.87 MB bf16 [4096][2304]
  ushort_t* obuf = (ushort_t*)(ws + 102760448);     //  16.78 MB bf16 [4096][2048]
  ushort_t* vt   = (ushort_t*)(ws + 119537664);     //   1.05 MB bf16 [2][128][2048]
  float*    bq   = (float*)(ws + 120586240);        //   9 KB  f32 [2304]
  ushort_t* ffb  = (ushort_t*)(ws + 120595456);     //  67.11 MB bf16 [4096][8192]
  if (ws_size < (size_t)187704320) return;

  dim3 t256(256), t512(512), t32x8(32, 8);

  // LN1
  ln_kernel<<<4096, t256, 0, stream>>>(x, ln1_s, ln1_b, hbuf);
  // fused QKV weights -> bf16 [2304][2048] transposed, plus bias concat
  concat_bias<<<9, t256, 0, stream>>>(wq_b, wk_b, wv_b, bq);
  transpose_convert<<<dim3(64, 64), t32x8, 0, stream>>>(wq_k, wt, 2048, 2048);
  transpose_convert<<<dim3(4, 64), t32x8, 0, stream>>>(wk_k, wt + (size_t)2048 * 2048, 2048, 128);
  transpose_convert<<<dim3(4, 64), t32x8, 0, stream>>>(wv_k, wt + (size_t)2176 * 2048, 2048, 128);
  // QKV projection (N = 2304): grid 16x9 = 144 blocks (row-major over N)
  gemm_bt<0><<<144, t512, 0, stream>>>(hbuf, wt, qkv, bq, nullptr, QKVN, 2048, 9);
  // V transpose for attention's PV operand
  transpose_v<<<dim3(64, 4, 2), t32x8, 0, stream>>>(qkv, vt);
  // attention
  flash_kernel<<<dim3(32, 16, 2), t256, 0, stream>>>(qkv, vt, obuf);
  // out-proj + residual -> xres (f32): grid 16x8 = 128 blocks
  transpose_convert<<<dim3(64, 64), t32x8, 0, stream>>>(wo_k, wt, 2048, 2048);
  gemm_bt<1><<<128, t512, 0, stream>>>(obuf, wt, xres, wo_b, x, 2048, 2048, 8);
  // LN2
  ln_kernel<<<4096, t256, 0, stream>>>(xres, ln2_s, ln2_b, hbuf);
  // FFN1 + exact GELU -> ffb (bf16): grid 16x32 = 512 blocks
  transpose_convert<<<dim3(256, 64), t32x8, 0, stream>>>(w1_k, wt, 2048, 8192);
  gemm_bt<2><<<512, t512, 0, stream>>>(hbuf, wt, ffb, w1_b, nullptr, 8192, 2048, 32);
  // FFN2 + residual -> d_out (f32): grid 16x8 = 128 blocks
  transpose_convert<<<dim3(64, 256), t32x8, 0, stream>>>(w2_k, wt, 8192, 2048);
  gemm_bt<1><<<128, t512, 0, stream>>>(ffb, wt, (float*)d_out, w2_b, xres, 2048, 8192, 8);
}

// Round 2
// 1071.207 us; speedup vs baseline: 2.3269x; 2.3269x over previous
//
#include <hip/hip_runtime.h>
#include <math.h>

typedef unsigned short ushort_t;
typedef __bf16 bf16x8 __attribute__((ext_vector_type(8)));
typedef float f32x4 __attribute__((ext_vector_type(4)));

#define SEQ 2048
#define DMODEL 2048
#define NBATCH 2
#define NHEAD 16
#define HDIM 128
#define FFDIM 8192
#define QKVN 2304   // 2048 (Q) + 128 (K) + 128 (V)

typedef __attribute__((address_space(1))) void as1_void;
typedef __attribute__((address_space(3))) void as3_void;

__device__ __forceinline__ void async_cp16(const void* g, void* l) {
  __builtin_amdgcn_global_load_lds((as1_void*)(void*)g, (as3_void*)l, 16, 0, 0);
}

__device__ __forceinline__ ushort_t f2bf(float f) {
  unsigned u = __float_as_uint(f);
  u += 0x7fff + ((u >> 16) & 1);   // round-to-nearest-even
  return (ushort_t)(u >> 16);
}

// compiler-level full fence + HW barrier + scheduler fence (rule #18/#21 armor)
__device__ __forceinline__ void block_bar() {
  __builtin_amdgcn_sched_barrier(0);
  asm volatile("" ::: "memory");
  __builtin_amdgcn_s_barrier();
  asm volatile("" ::: "memory");
  __builtin_amdgcn_sched_barrier(0);
}

#define S_VMCNT(n) asm volatile("s_waitcnt vmcnt(" #n ")" ::: "memory")

// ---------------- LayerNorm: f32 in -> bf16 out -------------------------
__global__ __launch_bounds__(256) void ln_kernel(const float* __restrict__ x,
    const float* __restrict__ gamma, const float* __restrict__ beta,
    ushort_t* __restrict__ out) {
  int row = blockIdx.x;
  int tid = threadIdx.x;
  const float4* xr = (const float4*)(x + (size_t)row * DMODEL);
  float4 a = xr[tid];
  float4 b = xr[256 + tid];
  float s  = a.x + a.y + a.z + a.w + b.x + b.y + b.z + b.w;
  float ss = a.x*a.x + a.y*a.y + a.z*a.z + a.w*a.w
           + b.x*b.x + b.y*b.y + b.z*b.z + b.w*b.w;
  for (int off = 1; off < 64; off <<= 1) {
    s  += __shfl_xor(s,  off, 64);
    ss += __shfl_xor(ss, off, 64);
  }
  __shared__ float red[8];
  int wave = tid >> 6, lane = tid & 63;
  if (lane == 0) { red[wave] = s; red[4 + wave] = ss; }
  __syncthreads();
  s  = red[0] + red[1] + red[2] + red[3];
  ss = red[4] + red[5] + red[6] + red[7];
  float mean = s * (1.0f / DMODEL);
  float var  = ss * (1.0f / DMODEL) - mean * mean;
  float rs   = rsqrtf(var + 1e-5f);
  const float4* g4 = (const float4*)gamma;
  const float4* b4 = (const float4*)beta;
  float4 g0 = g4[tid], g1 = g4[256 + tid];
  float4 e0 = b4[tid], e1 = b4[256 + tid];
  ushort_t* o = out + (size_t)row * DMODEL;
  ushort4 p0, p1;
  p0.x = f2bf((a.x - mean) * rs * g0.x + e0.x);
  p0.y = f2bf((a.y - mean) * rs * g0.y + e0.y);
  p0.z = f2bf((a.z - mean) * rs * g0.z + e0.z);
  p0.w = f2bf((a.w - mean) * rs * g0.w + e0.w);
  p1.x = f2bf((b.x - mean) * rs * g1.x + e1.x);
  p1.y = f2bf((b.y - mean) * rs * g1.y + e1.y);
  p1.z = f2bf((b.z - mean) * rs * g1.z + e1.z);
  p1.w = f2bf((b.w - mean) * rs * g1.w + e1.w);
  ((ushort4*)o)[tid]       = p0;
  ((ushort4*)o)[256 + tid] = p1;
}

// ------------- transpose + f32->bf16: src[Ks][Ns] -> dst[Ns][Ks] --------
__global__ __launch_bounds__(256) void transpose_convert(
    const float* __restrict__ src, ushort_t* __restrict__ dst, int Ks, int Ns) {
  __shared__ float tile[32][33];
  int nb = blockIdx.x * 32, kb = blockIdx.y * 32;
  int tx = threadIdx.x, ty = threadIdx.y;   // (32,8)
  for (int i = 0; i < 4; i++) {
    int k = kb + ty * 4 + i;
    tile[ty * 4 + i][tx] = src[(size_t)k * Ns + nb + tx];
  }
  __syncthreads();
  for (int i = 0; i < 4; i++) {
    int n = nb + ty * 4 + i;
    dst[(size_t)n * Ks + kb + tx] = f2bf(tile[tx][ty * 4 + i]);
  }
}

// ------------- V slice of qkv -> transposed vt[b][d][s] (bf16) ----------
__global__ __launch_bounds__(256) void transpose_v(
    const ushort_t* __restrict__ qkv, ushort_t* __restrict__ vt) {
  __shared__ ushort_t tile[32][33];
  int sb = blockIdx.x * 32, db = blockIdx.y * 32, b = blockIdx.z;
  int tx = threadIdx.x, ty = threadIdx.y;
  for (int i = 0; i < 4; i++) {
    int s = sb + ty * 4 + i;
    tile[ty * 4 + i][tx] = qkv[((size_t)(b * SEQ + s)) * QKVN + 2176 + db + tx];
  }
  __syncthreads();
  for (int i = 0; i < 4; i++) {
    int d = db + ty * 4 + i;
    vt[((size_t)(b * HDIM + d)) * SEQ + sb + tx] = tile[tx][ty * 4 + i];
  }
}

// ------------- concat q/k/v biases into one [2304] vector ---------------
__global__ void concat_bias(const float* __restrict__ qb, const float* __restrict__ kb,
                            const float* __restrict__ vb, float* __restrict__ dst) {
  int i = blockIdx.x * 256 + threadIdx.x;
  if (i < 2048) dst[i] = qb[i];
  else if (i < 2176) dst[i] = kb[i - 2048];
  else if (i < 2304) dst[i] = vb[i - 2176];
}

// ------------- GEMM 128x128 (r0 structure) + XCD-chunked swizzle --------
// MODE 0: bf16 out = acc + bias ; MODE 1: f32 out = resid + acc + bias ;
// MODE 2: bf16 out = gelu(acc + bias)
// 1-D grid (nwg % 8 == 0). swz groups each XCD's blocks into a contiguous
// run of the bm-major linear index -> A-panel stays in that XCD's L2.
template <int MODE>
__global__ __launch_bounds__(256) void gemm_bt(const ushort_t* __restrict__ A,
    const ushort_t* __restrict__ Bt, void* __restrict__ Cv,
    const float* __restrict__ bias, const float* __restrict__ resid,
    int N, int K, int GN) {
  __shared__ ushort_t sA[2][128 * 32];
  __shared__ ushort_t sB[2][128 * 32];
  int nwg = gridDim.x;
  int wg = blockIdx.x;
  int swz = (wg & 7) * (nwg >> 3) + (wg >> 3);
  int bm = swz / GN, bn = swz % GN;
  int tid = threadIdx.x, wave = tid >> 6, lane = tid & 63;
  int quad = lane >> 4, l16 = lane & 15;
  int wm = wave >> 1, wn = wave & 1;
  f32x4 acc[4][4];
  for (int i = 0; i < 4; i++)
    for (int j = 0; j < 4; j++) { f32x4 z = {0.f, 0.f, 0.f, 0.f}; acc[i][j] = z; }
  const ushort_t* Ab = A + (size_t)(bm * 128) * K;
  const ushort_t* Bb = Bt + (size_t)(bn * 128) * K;
  int cb = wave * 128;
  int c0 = cb + lane;
  size_t arow = (size_t)(c0 >> 2) * K + (c0 & 3) * 8;
  size_t arow1 = (size_t)((c0 + 64) >> 2) * K + ((c0 + 64) & 3) * 8;
  int nk = K >> 5;
  async_cp16(Ab + arow, &sA[0][cb * 8]);
  async_cp16(Ab + arow1, &sA[0][(cb + 64) * 8]);
  async_cp16(Bb + arow, &sB[0][cb * 8]);
  async_cp16(Bb + arow1, &sB[0][(cb + 64) * 8]);
  for (int ki = 0; ki < nk; ki++) {
    int cur = ki & 1;
    __syncthreads();
    if (ki + 1 < nk) {
      int k0 = (ki + 1) << 5;
      async_cp16(Ab + arow + k0, &sA[cur ^ 1][cb * 8]);
      async_cp16(Ab + arow1 + k0, &sA[cur ^ 1][(cb + 64) * 8]);
      async_cp16(Bb + arow + k0, &sB[cur ^ 1][cb * 8]);
      async_cp16(Bb + arow1 + k0, &sB[cur ^ 1][(cb + 64) * 8]);
    }
    bf16x8 af[4], bf[4];
    for (int i = 0; i < 4; i++)
      af[i] = *(const bf16x8*)(&sA[cur][(wm * 64 + i * 16 + l16) * 32 + quad * 8]);
    for (int j = 0; j < 4; j++)
      bf[j] = *(const bf16x8*)(&sB[cur][(wn * 64 + j * 16 + l16) * 32 + quad * 8]);
    for (int i = 0; i < 4; i++)
      for (int j = 0; j < 4; j++)
        acc[i][j] = __builtin_amdgcn_mfma_f32_16x16x32_bf16(af[i], bf[j], acc[i][j], 0, 0, 0);
  }
  for (int i = 0; i < 4; i++) {
    for (int r = 0; r < 4; r++) {
      size_t row = (size_t)(bm * 128 + wm * 64 + i * 16 + quad * 4 + r);
      for (int j = 0; j < 4; j++) {
        int col = bn * 128 + wn * 64 + j * 16 + l16;
        float v = acc[i][j][r] + bias[col];
        size_t idx = row * (size_t)N + col;
        if (MODE == 0) {
          ((ushort_t*)Cv)[idx] = f2bf(v);
        } else if (MODE == 1) {
          ((float*)Cv)[idx] = resid[idx] + v;
        } else {
          float g = 0.5f * v * (1.0f + erff(v * 0.70710678118654752f));
          ((ushort_t*)Cv)[idx] = f2bf(g);
        }
      }
    }
  }
}

// ---- 8-phase 256x256 GEMM (T2+T3+T4+T5), for large-N GEMMs (FFN1) ------
// 512 thr = 8 waves (2M x 4N), BK=64 as 2 k-slices of 32. LDS 128 KB:
// [2 buf][2 ks][256 rows][32 cols] bf16 per operand. Per tile, 4 phases:
//   p1: read A[i0-3]k0+B[*]k0, stage next A-k0, bar, 16 MFMA, bar
//   p2: read A[i4-7]k0,        stage next B-k0, bar, 16 MFMA, vmcnt(4), bar
//   p3: read A[i0-3]k1+B[*]k1, stage next A-k1, bar, 16 MFMA, bar
//   p4: read A[i4-7]k1,        stage next B-k1, bar, 16 MFMA, vmcnt(4), bar
// FIFO: regions issue in order Ak0,Bk0,Ak1,Bk1 per tile (2 loads each), so
// vmcnt(4) at p2-end guarantees this tile's k1 regions landed, vmcnt(4) at
// p4-end guarantees the NEXT tile's k0 regions landed. Never 0 mid-loop.
// LDS XOR swizzle (both-sides, rule #21): data (row,q) stored at chunk
// row*4 + (q ^ ((row>>1)&3)); staging pre-swizzles the GLOBAL source so
// global_load_lds's linear dest lands it there; reads apply the same XOR.
__device__ __forceinline__ const bf16x8* frag_ptr(const ushort_t* base, int row, int quad) {
  int off = quad ^ ((row >> 1) & 3);
  return (const bf16x8*)(base + ((size_t)(row * 4 + off)) * 8);
}

template <int MODE>
__global__ __launch_bounds__(512) void gemm_bt_8p(const ushort_t* __restrict__ A,
    const ushort_t* __restrict__ Bt, void* __restrict__ Cv,
    const float* __restrict__ bias, const float* __restrict__ resid,
    int N, int K, int GN) {
  __shared__ ushort_t sA[2][2][256 * 32];
  __shared__ ushort_t sB[2][2][256 * 32];
  int nwg = gridDim.x;
  int wg = blockIdx.x;
  int swz = (wg & 7) * (nwg >> 3) + (wg >> 3);
  int bm = swz / GN, bn = swz % GN;
  int tid = threadIdx.x, wave = tid >> 6, lane = tid & 63;
  int quad = lane >> 4, l16 = lane & 15;
  int wm = wave >> 2, wn = wave & 3;
  f32x4 acc[8][4];
  for (int i = 0; i < 8; i++)
    for (int j = 0; j < 4; j++) { f32x4 z = {0.f, 0.f, 0.f, 0.f}; acc[i][j] = z; }
  const ushort_t* Ab = A  + (size_t)(bm * 256) * K;
  const ushort_t* Bb = Bt + (size_t)(bn * 256) * K;
  // this thread's two 16B chunks per 16KB region (1024 chunks, 512 thr)
  int ca = wave * 64 + lane;          // load 0 chunk
  int cb2 = 512 + wave * 64 + lane;   // load 1 chunk
  int ra = ca >> 2,  qa = (ca & 3)  ^ ((ra >> 1) & 3);
  int rb = cb2 >> 2, qb2 = (cb2 & 3) ^ ((rb >> 1) & 3);
  size_t off0 = (size_t)ra * K + qa * 8;    // pre-swizzled global offsets
  size_t off1 = (size_t)rb * K + qb2 * 8;
  int lb0 = (wave * 64) * 8;          // wave-uniform LDS bases (ushort idx)
  int lb1 = (512 + wave * 64) * 8;
  // stage one region (operand X, buffer bb, k-slice ks, tile k-base kk)
#define STG8(SS, Xb, bb, ks, kk) do { \
    async_cp16((Xb) + off0 + (size_t)((kk) + (ks) * 32), &SS[bb][ks][lb0]); \
    async_cp16((Xb) + off1 + (size_t)((kk) + (ks) * 32), &SS[bb][ks][lb1]); \
  } while (0)

  int NT = K >> 6;
  // prologue: tile 0, regions in FIFO order Ak0,Bk0,Ak1,Bk1
  STG8(sA, Ab, 0, 0, 0);
  STG8(sB, Bb, 0, 0, 0);
  STG8(sA, Ab, 0, 1, 0);
  STG8(sB, Bb, 0, 1, 0);
  S_VMCNT(4);          // k0 regions landed (k1 still in flight)
  block_bar();

  bf16x8 a[4], b[4];
  for (int t = 0; t < NT; t++) {
    int cur = t & 1, nxt = cur ^ 1;
    bool more = (t + 1 < NT);
    int kk = (t + 1) << 6;
    const ushort_t* A0 = &sA[cur][0][0];
    const ushort_t* B0 = &sB[cur][0][0];
    const ushort_t* A1 = &sA[cur][1][0];
    const ushort_t* B1 = &sB[cur][1][0];
    // ---------------- phase 1 (i0-3, k0) ----------------
    for (int i = 0; i < 4; i++) a[i] = *frag_ptr(A0, wm * 128 + i * 16 + l16, quad);
    for (int j = 0; j < 4; j++) b[j] = *frag_ptr(B0, wn * 64 + j * 16 + l16, quad);
    if (more) STG8(sA, Ab, nxt, 0, kk);
    block_bar();
    __builtin_amdgcn_s_setprio(1);
    for (int i = 0; i < 4; i++)
      for (int j = 0; j < 4; j++)
        acc[i][j] = __builtin_amdgcn_mfma_f32_16x16x32_bf16(a[i], b[j], acc[i][j], 0, 0, 0);
    __builtin_amdgcn_s_setprio(0);
    block_bar();
    // ---------------- phase 2 (i4-7, k0) ----------------
    for (int i = 0; i < 4; i++) a[i] = *frag_ptr(A0, wm * 128 + 64 + i * 16 + l16, quad);
    if (more) STG8(sB, Bb, nxt, 0, kk);
    block_bar();
    __builtin_amdgcn_s_setprio(1);
    for (int i = 0; i < 4; i++)
      for (int j = 0; j < 4; j++)
        acc[4 + i][j] = __builtin_amdgcn_mfma_f32_16x16x32_bf16(a[i], b[j], acc[4 + i][j], 0, 0, 0);
    __builtin_amdgcn_s_setprio(0);
    if (more) { S_VMCNT(4); } else { S_VMCNT(0); }   // this tile's k1 landed
    block_bar();
    // ---------------- phase 3 (i0-3, k1) ----------------
    for (int i = 0; i < 4; i++) a[i] = *frag_ptr(A1, wm * 128 + i * 16 + l16, quad);
    for (int j = 0; j < 4; j++) b[j] = *frag_ptr(B1, wn * 64 + j * 16 + l16, quad);
    if (more) STG8(sA, Ab, nxt, 1, kk);
    block_bar();
    __builtin_amdgcn_s_setprio(1);
    for (int i = 0; i < 4; i++)
      for (int j = 0; j < 4; j++)
        acc[i][j] = __builtin_amdgcn_mfma_f32_16x16x32_bf16(a[i], b[j], acc[i][j], 0, 0, 0);
    __builtin_amdgcn_s_setprio(0);
    block_bar();
    // ---------------- phase 4 (i4-7, k1) ----------------
    for (int i = 0; i < 4; i++) a[i] = *frag_ptr(A1, wm * 128 + 64 + i * 16 + l16, quad);
    if (more) STG8(sB, Bb, nxt, 1, kk);
    block_bar();
    __builtin_amdgcn_s_setprio(1);
    for (int i = 0; i < 4; i++)
      for (int j = 0; j < 4; j++)
        acc[4 + i][j] = __builtin_amdgcn_mfma_f32_16x16x32_bf16(a[i], b[j], acc[4 + i][j], 0, 0, 0);
    __builtin_amdgcn_s_setprio(0);
    if (more) { S_VMCNT(4); }   // next tile's k0 landed
    block_bar();
  }
#undef STG8
  for (int i = 0; i < 8; i++) {
    for (int r = 0; r < 4; r++) {
      size_t row = (size_t)(bm * 256 + wm * 128 + i * 16 + quad * 4 + r);
      for (int j = 0; j < 4; j++) {
        int col = bn * 256 + wn * 64 + j * 16 + l16;
        float v = acc[i][j][r] + bias[col];
        size_t idx = row * (size_t)N + col;
        if (MODE == 0) {
          ((ushort_t*)Cv)[idx] = f2bf(v);
        } else if (MODE == 1) {
          ((float*)Cv)[idx] = resid[idx] + v;
        } else {
          float g = 0.5f * v * (1.0f + erff(v * 0.70710678118654752f));
          ((ushort_t*)Cv)[idx] = f2bf(g);
        }
      }
    }
  }
}

// ------------- Flash attention (causal, MQA) ----------------------------
// grid (S/64, H, B), block 256 = 4 waves; wave owns 16 q-rows.
__global__ __launch_bounds__(256) void flash_kernel(const ushort_t* __restrict__ qkv,
    const ushort_t* __restrict__ vt, ushort_t* __restrict__ obuf) {
  __shared__ ushort_t sK[64 * 128];    // K tile  [64 keys][128 d]
  __shared__ ushort_t sVT[128 * 64];   // V^T tile [128 d][64 keys]
  __shared__ ushort_t sP[4][16 * 64];  // per-wave P relayout buffer
  int qt = blockIdx.x, h = blockIdx.y, b = blockIdx.z;
  int tid = threadIdx.x, wave = tid >> 6, lane = tid & 63;
  int quad = lane >> 4, l16 = lane & 15;
  int qb = qt * 64 + wave * 16;
  size_t batch_off = (size_t)b * SEQ * QKVN;

  bf16x8 aq[4];
  {
    const ushort_t* qp = qkv + batch_off + (size_t)(qb + l16) * QKVN + h * HDIM + quad * 8;
    for (int c = 0; c < 4; c++) aq[c] = *(const bf16x8*)(qp + c * 32);
  }
  f32x4 oacc[8];
  for (int i = 0; i < 8; i++) { f32x4 z = {0.f, 0.f, 0.f, 0.f}; oacc[i] = z; }
  float m_i[4], l_i[4];
  for (int r = 0; r < 4; r++) { m_i[r] = -1e30f; l_i[r] = 0.f; }
  const float scale = 0.08838834764831845f;  // 1/sqrt(128)

  for (int kt = 0; kt <= qt; kt++) {
    __syncthreads();   // previous iteration done with sK/sVT
    for (int t = 0; t < 4; t++) {
      int cb = wave * 256 + t * 64;
      int c  = cb + lane;
      async_cp16(qkv + batch_off + (size_t)(kt * 64 + (c >> 4)) * QKVN + 2048 + (c & 15) * 8,
                 &sK[cb * 8]);
      async_cp16(vt + ((size_t)(b * HDIM + (c >> 3))) * SEQ + kt * 64 + (c & 7) * 8,
                 &sVT[cb * 8]);
    }
    __syncthreads();   // staged (compiler drains vmcnt before barrier)

    // Q K^T
    f32x4 sc[4];
    for (int j = 0; j < 4; j++) {
      f32x4 z = {0.f, 0.f, 0.f, 0.f};
      for (int c = 0; c < 4; c++) {
        bf16x8 bk = *(const bf16x8*)(&sK[(j * 16 + l16) * 128 + c * 32 + quad * 8]);
        z = __builtin_amdgcn_mfma_f32_16x16x32_bf16(aq[c], bk, z, 0, 0, 0);
      }
      sc[j] = z;
    }
    // scale + causal mask + online softmax
    float rmax[4] = {-1e30f, -1e30f, -1e30f, -1e30f};
    for (int j = 0; j < 4; j++) {
      int col = kt * 64 + j * 16 + l16;
      for (int r = 0; r < 4; r++) {
        int rowg = qb + quad * 4 + r;
        float v = (col <= rowg) ? sc[j][r] * scale : -1e30f;
        sc[j][r] = v;
        rmax[r] = fmaxf(rmax[r], v);
      }
    }
    for (int off = 1; off < 16; off <<= 1)
      for (int r = 0; r < 4; r++) rmax[r] = fmaxf(rmax[r], __shfl_xor(rmax[r], off, 64));
    float alpha[4], psum[4];
    for (int r = 0; r < 4; r++) {
      float mn = fmaxf(m_i[r], rmax[r]);
      alpha[r] = __expf(m_i[r] - mn);
      m_i[r] = mn;
      psum[r] = 0.f;
    }
    for (int j = 0; j < 4; j++)
      for (int r = 0; r < 4; r++) {
        float p = __expf(sc[j][r] - m_i[r]);
        sc[j][r] = p;
        psum[r] += p;
      }
    for (int off = 1; off < 16; off <<= 1)
      for (int r = 0; r < 4; r++) psum[r] += __shfl_xor(psum[r], off, 64);
    for (int r = 0; r < 4; r++) l_i[r] = l_i[r] * alpha[r] + psum[r];
    for (int i = 0; i < 8; i++)
      for (int r = 0; r < 4; r++) oacc[i][r] *= alpha[r];

    // P: C-layout -> A-layout via per-wave LDS roundtrip
    for (int j = 0; j < 4; j++)
      for (int r = 0; r < 4; r++)
        sP[wave][(quad * 4 + r) * 64 + j * 16 + l16] = f2bf(sc[j][r]);
    asm volatile("s_waitcnt lgkmcnt(0)" ::: "memory");
    bf16x8 pa[2];
    for (int c = 0; c < 2; c++)
      pa[c] = *(const bf16x8*)(&sP[wave][l16 * 64 + c * 32 + quad * 8]);
    // P V
    for (int ds = 0; ds < 8; ds++)
      for (int c = 0; c < 2; c++) {
        bf16x8 vb = *(const bf16x8*)(&sVT[(ds * 16 + l16) * 64 + c * 32 + quad * 8]);
        oacc[ds] = __builtin_amdgcn_mfma_f32_16x16x32_bf16(pa[c], vb, oacc[ds], 0, 0, 0);
      }
  }
  for (int r = 0; r < 4; r++) {
    float inv = 1.0f / l_i[r];
    size_t rowo = ((size_t)(b * SEQ + qb + quad * 4 + r)) * DMODEL + h * HDIM;
    for (int ds = 0; ds < 8; ds++)
      obuf[rowo + ds * 16 + l16] = f2bf(oacc[ds][r] * inv);
  }
}

// ------------------------------------------------------------------------
extern "C" void kernel_launch(void* const* d_in, const int* in_sizes, int n_in,
                              void* d_out, int out_size, void* d_ws, size_t ws_size,
                              hipStream_t stream) {
  const float* x     = (const float*)d_in[0];
  const float* wq_k  = (const float*)d_in[2];
  const float* wq_b  = (const float*)d_in[3];
  const float* wk_k  = (const float*)d_in[4];
  const float* wk_b  = (const float*)d_in[5];
  const float* wv_k  = (const float*)d_in[6];
  const float* wv_b  = (const float*)d_in[7];
  const float* wo_k  = (const float*)d_in[8];
  const float* wo_b  = (const float*)d_in[9];
  const float* w1_k  = (const float*)d_in[10];
  const float* w1_b  = (const float*)d_in[11];
  const float* w2_k  = (const float*)d_in[12];
  const float* w2_b  = (const float*)d_in[13];
  const float* ln1_s = (const float*)d_in[14];
  const float* ln1_b = (const float*)d_in[15];
  const float* ln2_s = (const float*)d_in[16];
  const float* ln2_b = (const float*)d_in[17];

  // workspace layout (bytes, all 256-aligned); total ~188 MB
  char* ws = (char*)d_ws;
  float*    xres = (float*)(ws + 0);                //  33.55 MB f32 [4096][2048]
  ushort_t* hbuf = (ushort_t*)(ws + 33554432);      //  16.78 MB bf16 [4096][2048]
  ushort_t* wt   = (ushort_t*)(ws + 50331648);      //  33.55 MB bf16 weight scratch
  ushort_t* qkv  = (ushort_t*)(ws + 83886080);      //  18.87 MB bf16 [4096][2304]
  ushort_t* obuf = (ushort_t*)(ws + 102760448);     //  16.78 MB bf16 [4096][2048]
  ushort_t* vt   = (ushort_t*)(ws + 119537664);     //   1.05 MB bf16 [2][128][2048]
  float*    bq   = (float*)(ws + 120586240);        //   9 KB  f32 [2304]
  ushort_t* ffb  = (ushort_t*)(ws + 120595456);     //  67.11 MB bf16 [4096][8192]
  if (ws_size < (size_t)187704320) return;

  dim3 t256(256), t512(512), t32x8(32, 8);

  // LN1
  ln_kernel<<<4096, t256, 0, stream>>>(x, ln1_s, ln1_b, hbuf);
  // fused QKV weights -> bf16 [2304][2048] transposed, plus bias concat
  concat_bias<<<9, t256, 0, stream>>>(wq_b, wk_b, wv_b, bq);
  transpose_convert<<<dim3(64, 64), t32x8, 0, stream>>>(wq_k, wt, 2048, 2048);
  transpose_convert<<<dim3(4, 64), t32x8, 0, stream>>>(wk_k, wt + (size_t)2048 * 2048, 2048, 128);
  transpose_convert<<<dim3(4, 64), t32x8, 0, stream>>>(wv_k, wt + (size_t)2176 * 2048, 2048, 128);
  // QKV projection (N = 2304): 18x32 = 576 blocks, 128^2 tiles
  gemm_bt<0><<<576, t256, 0, stream>>>(hbuf, wt, qkv, bq, nullptr, QKVN, 2048, 18);
  // V transpose for attention's PV operand
  transpose_v<<<dim3(64, 4, 2), t32x8, 0, stream>>>(qkv, vt);
  // attention
  flash_kernel<<<dim3(32, 16, 2), t256, 0, stream>>>(qkv, vt, obuf);
  // out-proj + residual -> xres (f32): 16x32 = 512 blocks, 128^2 tiles
  transpose_convert<<<dim3(64, 64), t32x8, 0, stream>>>(wo_k, wt, 2048, 2048);
  gemm_bt<1><<<512, t256, 0, stream>>>(obuf, wt, xres, wo_b, x, 2048, 2048, 16);
  // LN2
  ln_kernel<<<4096, t256, 0, stream>>>(xres, ln2_s, ln2_b, hbuf);
  // FFN1 + exact GELU -> ffb (bf16): 32x16 = 512 blocks, 256^2 8-phase
  transpose_convert<<<dim3(256, 64), t32x8, 0, stream>>>(w1_k, wt, 2048, 8192);
  gemm_bt_8p<2><<<512, t512, 0, stream>>>(hbuf, wt, ffb, w1_b, nullptr, 8192, 2048, 32);
  // FFN2 + residual -> d_out (f32): 16x32 = 512 blocks, 128^2 tiles
  transpose_convert<<<dim3(64, 256), t32x8, 0, stream>>>(w2_k, wt, 8192, 2048);
  gemm_bt<1><<<512, t256, 0, stream>>>(ffb, wt, (float*)d_out, w2_b, xres, 2048, 8192, 16);
}

// Round 3
// 969.534 us; speedup vs baseline: 2.5709x; 1.1049x over previous
//
#include <hip/hip_runtime.h>
#include <math.h>

typedef unsigned short ushort_t;
typedef __bf16 bf16x8 __attribute__((ext_vector_type(8)));
typedef float f32x4 __attribute__((ext_vector_type(4)));

#define SEQ 2048
#define DMODEL 2048
#define NBATCH 2
#define NHEAD 16
#define HDIM 128
#define FFDIM 8192
#define QKVN 2304   // 2048 (Q) + 128 (K) + 128 (V)

typedef __attribute__((address_space(1))) void as1_void;
typedef __attribute__((address_space(3))) void as3_void;

__device__ __forceinline__ void async_cp16(const void* g, void* l) {
  __builtin_amdgcn_global_load_lds((as1_void*)(void*)g, (as3_void*)l, 16, 0, 0);
}

__device__ __forceinline__ ushort_t f2bf(float f) {
  unsigned u = __float_as_uint(f);
  u += 0x7fff + ((u >> 16) & 1);   // round-to-nearest-even
  return (ushort_t)(u >> 16);
}

// compiler-level full fence + HW barrier + scheduler fence (rule #18/#21 armor)
__device__ __forceinline__ void block_bar() {
  __builtin_amdgcn_sched_barrier(0);
  asm volatile("" ::: "memory");
  __builtin_amdgcn_s_barrier();
  asm volatile("" ::: "memory");
  __builtin_amdgcn_sched_barrier(0);
}

#define S_VMCNT(n) asm volatile("s_waitcnt vmcnt(" #n ")" ::: "memory")

// ---------------- LayerNorm: f32 in -> bf16 out -------------------------
__global__ __launch_bounds__(256) void ln_kernel(const float* __restrict__ x,
    const float* __restrict__ gamma, const float* __restrict__ beta,
    ushort_t* __restrict__ out) {
  int row = blockIdx.x;
  int tid = threadIdx.x;
  const float4* xr = (const float4*)(x + (size_t)row * DMODEL);
  float4 a = xr[tid];
  float4 b = xr[256 + tid];
  float s  = a.x + a.y + a.z + a.w + b.x + b.y + b.z + b.w;
  float ss = a.x*a.x + a.y*a.y + a.z*a.z + a.w*a.w
           + b.x*b.x + b.y*b.y + b.z*b.z + b.w*b.w;
  for (int off = 1; off < 64; off <<= 1) {
    s  += __shfl_xor(s,  off, 64);
    ss += __shfl_xor(ss, off, 64);
  }
  __shared__ float red[8];
  int wave = tid >> 6, lane = tid & 63;
  if (lane == 0) { red[wave] = s; red[4 + wave] = ss; }
  __syncthreads();
  s  = red[0] + red[1] + red[2] + red[3];
  ss = red[4] + red[5] + red[6] + red[7];
  float mean = s * (1.0f / DMODEL);
  float var  = ss * (1.0f / DMODEL) - mean * mean;
  float rs   = rsqrtf(var + 1e-5f);
  const float4* g4 = (const float4*)gamma;
  const float4* b4 = (const float4*)beta;
  float4 g0 = g4[tid], g1 = g4[256 + tid];
  float4 e0 = b4[tid], e1 = b4[256 + tid];
  ushort_t* o = out + (size_t)row * DMODEL;
  ushort4 p0, p1;
  p0.x = f2bf((a.x - mean) * rs * g0.x + e0.x);
  p0.y = f2bf((a.y - mean) * rs * g0.y + e0.y);
  p0.z = f2bf((a.z - mean) * rs * g0.z + e0.z);
  p0.w = f2bf((a.w - mean) * rs * g0.w + e0.w);
  p1.x = f2bf((b.x - mean) * rs * g1.x + e1.x);
  p1.y = f2bf((b.y - mean) * rs * g1.y + e1.y);
  p1.z = f2bf((b.z - mean) * rs * g1.z + e1.z);
  p1.w = f2bf((b.w - mean) * rs * g1.w + e1.w);
  ((ushort4*)o)[tid]       = p0;
  ((ushort4*)o)[256 + tid] = p1;
}

// ------------- transpose + f32->bf16: src[Ks][Ns] -> dst[Ns][Ks] --------
__global__ __launch_bounds__(256) void transpose_convert(
    const float* __restrict__ src, ushort_t* __restrict__ dst, int Ks, int Ns) {
  __shared__ float tile[32][33];
  int nb = blockIdx.x * 32, kb = blockIdx.y * 32;
  int tx = threadIdx.x, ty = threadIdx.y;   // (32,8)
  for (int i = 0; i < 4; i++) {
    int k = kb + ty * 4 + i;
    tile[ty * 4 + i][tx] = src[(size_t)k * Ns + nb + tx];
  }
  __syncthreads();
  for (int i = 0; i < 4; i++) {
    int n = nb + ty * 4 + i;
    dst[(size_t)n * Ks + kb + tx] = f2bf(tile[tx][ty * 4 + i]);
  }
}

// ------------- V slice of qkv -> transposed vt[b][d][s] (bf16) ----------
__global__ __launch_bounds__(256) void transpose_v(
    const ushort_t* __restrict__ qkv, ushort_t* __restrict__ vt) {
  __shared__ ushort_t tile[32][33];
  int sb = blockIdx.x * 32, db = blockIdx.y * 32, b = blockIdx.z;
  int tx = threadIdx.x, ty = threadIdx.y;
  for (int i = 0; i < 4; i++) {
    int s = sb + ty * 4 + i;
    tile[ty * 4 + i][tx] = qkv[((size_t)(b * SEQ + s)) * QKVN + 2176 + db + tx];
  }
  __syncthreads();
  for (int i = 0; i < 4; i++) {
    int d = db + ty * 4 + i;
    vt[((size_t)(b * HDIM + d)) * SEQ + sb + tx] = tile[tx][ty * 4 + i];
  }
}

// ------------- concat q/k/v biases into one [2304] vector ---------------
__global__ void concat_bias(const float* __restrict__ qb, const float* __restrict__ kb,
                            const float* __restrict__ vb, float* __restrict__ dst) {
  int i = blockIdx.x * 256 + threadIdx.x;
  if (i < 2048) dst[i] = qb[i];
  else if (i < 2176) dst[i] = kb[i - 2048];
  else if (i < 2304) dst[i] = vb[i - 2176];
}

// ------------- GEMM 128x128 (r0 structure) + XCD-chunked swizzle --------
// MODE 0: bf16 out = acc + bias ; MODE 1: f32 out = resid + acc + bias ;
// MODE 2: bf16 out = gelu(acc + bias)
template <int MODE>
__global__ __launch_bounds__(256) void gemm_bt(const ushort_t* __restrict__ A,
    const ushort_t* __restrict__ Bt, void* __restrict__ Cv,
    const float* __restrict__ bias, const float* __restrict__ resid,
    int N, int K, int GN) {
  __shared__ ushort_t sA[2][128 * 32];
  __shared__ ushort_t sB[2][128 * 32];
  int nwg = gridDim.x;
  int wg = blockIdx.x;
  int swz = (wg & 7) * (nwg >> 3) + (wg >> 3);
  int bm = swz / GN, bn = swz % GN;
  int tid = threadIdx.x, wave = tid >> 6, lane = tid & 63;
  int quad = lane >> 4, l16 = lane & 15;
  int wm = wave >> 1, wn = wave & 1;
  f32x4 acc[4][4];
  for (int i = 0; i < 4; i++)
    for (int j = 0; j < 4; j++) { f32x4 z = {0.f, 0.f, 0.f, 0.f}; acc[i][j] = z; }
  const ushort_t* Ab = A + (size_t)(bm * 128) * K;
  const ushort_t* Bb = Bt + (size_t)(bn * 128) * K;
  int cb = wave * 128;
  int c0 = cb + lane;
  size_t arow = (size_t)(c0 >> 2) * K + (c0 & 3) * 8;
  size_t arow1 = (size_t)((c0 + 64) >> 2) * K + ((c0 + 64) & 3) * 8;
  int nk = K >> 5;
  async_cp16(Ab + arow, &sA[0][cb * 8]);
  async_cp16(Ab + arow1, &sA[0][(cb + 64) * 8]);
  async_cp16(Bb + arow, &sB[0][cb * 8]);
  async_cp16(Bb + arow1, &sB[0][(cb + 64) * 8]);
  for (int ki = 0; ki < nk; ki++) {
    int cur = ki & 1;
    __syncthreads();
    if (ki + 1 < nk) {
      int k0 = (ki + 1) << 5;
      async_cp16(Ab + arow + k0, &sA[cur ^ 1][cb * 8]);
      async_cp16(Ab + arow1 + k0, &sA[cur ^ 1][(cb + 64) * 8]);
      async_cp16(Bb + arow + k0, &sB[cur ^ 1][cb * 8]);
      async_cp16(Bb + arow1 + k0, &sB[cur ^ 1][(cb + 64) * 8]);
    }
    bf16x8 af[4], bf[4];
    for (int i = 0; i < 4; i++)
      af[i] = *(const bf16x8*)(&sA[cur][(wm * 64 + i * 16 + l16) * 32 + quad * 8]);
    for (int j = 0; j < 4; j++)
      bf[j] = *(const bf16x8*)(&sB[cur][(wn * 64 + j * 16 + l16) * 32 + quad * 8]);
    for (int i = 0; i < 4; i++)
      for (int j = 0; j < 4; j++)
        acc[i][j] = __builtin_amdgcn_mfma_f32_16x16x32_bf16(af[i], bf[j], acc[i][j], 0, 0, 0);
  }
  for (int i = 0; i < 4; i++) {
    for (int r = 0; r < 4; r++) {
      size_t row = (size_t)(bm * 128 + wm * 64 + i * 16 + quad * 4 + r);
      for (int j = 0; j < 4; j++) {
        int col = bn * 128 + wn * 64 + j * 16 + l16;
        float v = acc[i][j][r] + bias[col];
        size_t idx = row * (size_t)N + col;
        if (MODE == 0) {
          ((ushort_t*)Cv)[idx] = f2bf(v);
        } else if (MODE == 1) {
          ((float*)Cv)[idx] = resid[idx] + v;
        } else {
          float g = 0.5f * v * (1.0f + erff(v * 0.70710678118654752f));
          ((ushort_t*)Cv)[idx] = f2bf(g);
        }
      }
    }
  }
}

// ---- 8-phase 256x256 GEMM (T2+T3+T4+T5), for large-N GEMMs (FFN1) ------
__device__ __forceinline__ const bf16x8* frag_ptr(const ushort_t* base, int row, int quad) {
  int off = quad ^ ((row >> 1) & 3);
  return (const bf16x8*)(base + ((size_t)(row * 4 + off)) * 8);
}

template <int MODE>
__global__ __launch_bounds__(512) void gemm_bt_8p(const ushort_t* __restrict__ A,
    const ushort_t* __restrict__ Bt, void* __restrict__ Cv,
    const float* __restrict__ bias, const float* __restrict__ resid,
    int N, int K, int GN) {
  __shared__ ushort_t sA[2][2][256 * 32];
  __shared__ ushort_t sB[2][2][256 * 32];
  int nwg = gridDim.x;
  int wg = blockIdx.x;
  int swz = (wg & 7) * (nwg >> 3) + (wg >> 3);
  int bm = swz / GN, bn = swz % GN;
  int tid = threadIdx.x, wave = tid >> 6, lane = tid & 63;
  int quad = lane >> 4, l16 = lane & 15;
  int wm = wave >> 2, wn = wave & 3;
  f32x4 acc[8][4];
  for (int i = 0; i < 8; i++)
    for (int j = 0; j < 4; j++) { f32x4 z = {0.f, 0.f, 0.f, 0.f}; acc[i][j] = z; }
  const ushort_t* Ab = A  + (size_t)(bm * 256) * K;
  const ushort_t* Bb = Bt + (size_t)(bn * 256) * K;
  int ca = wave * 64 + lane;
  int cb2 = 512 + wave * 64 + lane;
  int ra = ca >> 2,  qa = (ca & 3)  ^ ((ra >> 1) & 3);
  int rb = cb2 >> 2, qb2 = (cb2 & 3) ^ ((rb >> 1) & 3);
  size_t off0 = (size_t)ra * K + qa * 8;
  size_t off1 = (size_t)rb * K + qb2 * 8;
  int lb0 = (wave * 64) * 8;
  int lb1 = (512 + wave * 64) * 8;
#define STG8(SS, Xb, bb, ks, kk) do { \
    async_cp16((Xb) + off0 + (size_t)((kk) + (ks) * 32), &SS[bb][ks][lb0]); \
    async_cp16((Xb) + off1 + (size_t)((kk) + (ks) * 32), &SS[bb][ks][lb1]); \
  } while (0)

  int NT = K >> 6;
  STG8(sA, Ab, 0, 0, 0);
  STG8(sB, Bb, 0, 0, 0);
  STG8(sA, Ab, 0, 1, 0);
  STG8(sB, Bb, 0, 1, 0);
  S_VMCNT(4);
  block_bar();

  bf16x8 a[4], b[4];
  for (int t = 0; t < NT; t++) {
    int cur = t & 1, nxt = cur ^ 1;
    bool more = (t + 1 < NT);
    int kk = (t + 1) << 6;
    const ushort_t* A0 = &sA[cur][0][0];
    const ushort_t* B0 = &sB[cur][0][0];
    const ushort_t* A1 = &sA[cur][1][0];
    const ushort_t* B1 = &sB[cur][1][0];
    // ---------------- phase 1 (i0-3, k0) ----------------
    for (int i = 0; i < 4; i++) a[i] = *frag_ptr(A0, wm * 128 + i * 16 + l16, quad);
    for (int j = 0; j < 4; j++) b[j] = *frag_ptr(B0, wn * 64 + j * 16 + l16, quad);
    if (more) STG8(sA, Ab, nxt, 0, kk);
    block_bar();
    __builtin_amdgcn_s_setprio(1);
    for (int i = 0; i < 4; i++)
      for (int j = 0; j < 4; j++)
        acc[i][j] = __builtin_amdgcn_mfma_f32_16x16x32_bf16(a[i], b[j], acc[i][j], 0, 0, 0);
    __builtin_amdgcn_s_setprio(0);
    block_bar();
    // ---------------- phase 2 (i4-7, k0) ----------------
    for (int i = 0; i < 4; i++) a[i] = *frag_ptr(A0, wm * 128 + 64 + i * 16 + l16, quad);
    if (more) STG8(sB, Bb, nxt, 0, kk);
    block_bar();
    __builtin_amdgcn_s_setprio(1);
    for (int i = 0; i < 4; i++)
      for (int j = 0; j < 4; j++)
        acc[4 + i][j] = __builtin_amdgcn_mfma_f32_16x16x32_bf16(a[i], b[j], acc[4 + i][j], 0, 0, 0);
    __builtin_amdgcn_s_setprio(0);
    if (more) { S_VMCNT(4); } else { S_VMCNT(0); }
    block_bar();
    // ---------------- phase 3 (i0-3, k1) ----------------
    for (int i = 0; i < 4; i++) a[i] = *frag_ptr(A1, wm * 128 + i * 16 + l16, quad);
    for (int j = 0; j < 4; j++) b[j] = *frag_ptr(B1, wn * 64 + j * 16 + l16, quad);
    if (more) STG8(sA, Ab, nxt, 1, kk);
    block_bar();
    __builtin_amdgcn_s_setprio(1);
    for (int i = 0; i < 4; i++)
      for (int j = 0; j < 4; j++)
        acc[i][j] = __builtin_amdgcn_mfma_f32_16x16x32_bf16(a[i], b[j], acc[i][j], 0, 0, 0);
    __builtin_amdgcn_s_setprio(0);
    block_bar();
    // ---------------- phase 4 (i4-7, k1) ----------------
    for (int i = 0; i < 4; i++) a[i] = *frag_ptr(A1, wm * 128 + 64 + i * 16 + l16, quad);
    if (more) STG8(sB, Bb, nxt, 1, kk);
    block_bar();
    __builtin_amdgcn_s_setprio(1);
    for (int i = 0; i < 4; i++)
      for (int j = 0; j < 4; j++)
        acc[4 + i][j] = __builtin_amdgcn_mfma_f32_16x16x32_bf16(a[i], b[j], acc[4 + i][j], 0, 0, 0);
    __builtin_amdgcn_s_setprio(0);
    if (more) { S_VMCNT(4); }
    block_bar();
  }
#undef STG8
  for (int i = 0; i < 8; i++) {
    for (int r = 0; r < 4; r++) {
      size_t row = (size_t)(bm * 256 + wm * 128 + i * 16 + quad * 4 + r);
      for (int j = 0; j < 4; j++) {
        int col = bn * 256 + wn * 64 + j * 16 + l16;
        float v = acc[i][j][r] + bias[col];
        size_t idx = row * (size_t)N + col;
        if (MODE == 0) {
          ((ushort_t*)Cv)[idx] = f2bf(v);
        } else if (MODE == 1) {
          ((float*)Cv)[idx] = resid[idx] + v;
        } else {
          float g = 0.5f * v * (1.0f + erff(v * 0.70710678118654752f));
          ((ushort_t*)Cv)[idx] = f2bf(g);
        }
      }
    }
  }
}

// ------------- Flash attention (causal, MQA) ----------------------------
// grid (S/64, H, B), block 256 = 4 waves; wave owns 16 q-rows.
// LDS XOR-swizzle (T2 / G4, both-sides per rule #21): all three tiles have
// power-of-2 row strides (sK 256B, sVT/sP 128B) -> 16-32 way bank conflicts
// unswizzled. Store data chunk qd of row r at chunk qd ^ (r&7)
// (byte ^= (r&7)<<4). For sK/sVT (global_load_lds, linear dest) the
// permutation is applied to the GLOBAL source; reads apply the same XOR.
__global__ __launch_bounds__(256) void flash_kernel(const ushort_t* __restrict__ qkv,
    const ushort_t* __restrict__ vt, ushort_t* __restrict__ obuf) {
  __shared__ ushort_t sK[64 * 128];    // K tile  [64 keys][16 chunks] swizzled
  __shared__ ushort_t sVT[128 * 64];   // V^T tile [128 d][8 chunks] swizzled
  __shared__ ushort_t sP[4][16 * 64];  // per-wave P relayout buffer, swizzled
  int qt = blockIdx.x, h = blockIdx.y, b = blockIdx.z;
  int tid = threadIdx.x, wave = tid >> 6, lane = tid & 63;
  int quad = lane >> 4, l16 = lane & 15;
  int qb = qt * 64 + wave * 16;
  size_t batch_off = (size_t)b * SEQ * QKVN;

  bf16x8 aq[4];
  {
    const ushort_t* qp = qkv + batch_off + (size_t)(qb + l16) * QKVN + h * HDIM + quad * 8;
    for (int c = 0; c < 4; c++) aq[c] = *(const bf16x8*)(qp + c * 32);
  }
  f32x4 oacc[8];
  for (int i = 0; i < 8; i++) { f32x4 z = {0.f, 0.f, 0.f, 0.f}; oacc[i] = z; }
  float m_i[4], l_i[4];
  for (int r = 0; r < 4; r++) { m_i[r] = -1e30f; l_i[r] = 0.f; }
  const float scale = 0.08838834764831845f;  // 1/sqrt(128)

  for (int kt = 0; kt <= qt; kt++) {
    __syncthreads();   // previous iteration done with sK/sVT
    for (int t = 0; t < 4; t++) {
      int cb = wave * 256 + t * 64;
      int c  = cb + lane;
      // sK dest chunk c = (row=c>>4, st=c&15); source data chunk = st ^ (row&7)
      async_cp16(qkv + batch_off + (size_t)(kt * 64 + (c >> 4)) * QKVN + 2048
                     + (size_t)(((c & 15) ^ ((c >> 4) & 7)) * 8),
                 &sK[cb * 8]);
      // sVT dest chunk c = (row=c>>3, st=c&7); source data chunk = st ^ (row&7)
      async_cp16(vt + ((size_t)(b * HDIM + (c >> 3))) * SEQ + kt * 64
                    + (size_t)(((c & 7) ^ ((c >> 3) & 7)) * 8),
                 &sVT[cb * 8]);
    }
    __syncthreads();   // staged (compiler drains vmcnt before barrier)

    // Q K^T  (row = j*16+l16; data chunk c*4+quad read at chunk^(row&7))
    f32x4 sc[4];
    for (int j = 0; j < 4; j++) {
      f32x4 z = {0.f, 0.f, 0.f, 0.f};
      for (int c = 0; c < 4; c++) {
        bf16x8 bk = *(const bf16x8*)(&sK[(j * 16 + l16) * 128
                                         + (((c * 4 + quad) ^ (l16 & 7)) * 8)]);
        z = __builtin_amdgcn_mfma_f32_16x16x32_bf16(aq[c], bk, z, 0, 0, 0);
      }
      sc[j] = z;
    }
    // scale + causal mask + online softmax
    float rmax[4] = {-1e30f, -1e30f, -1e30f, -1e30f};
    for (int j = 0; j < 4; j++) {
      int col = kt * 64 + j * 16 + l16;
      for (int r = 0; r < 4; r++) {
        int rowg = qb + quad * 4 + r;
        float v = (col <= rowg) ? sc[j][r] * scale : -1e30f;
        sc[j][r] = v;
        rmax[r] = fmaxf(rmax[r], v);
      }
    }
    for (int off = 1; off < 16; off <<= 1)
      for (int r = 0; r < 4; r++) rmax[r] = fmaxf(rmax[r], __shfl_xor(rmax[r], off, 64));
    float alpha[4], psum[4];
    for (int r = 0; r < 4; r++) {
      float mn = fmaxf(m_i[r], rmax[r]);
      alpha[r] = __expf(m_i[r] - mn);
      m_i[r] = mn;
      psum[r] = 0.f;
    }
    for (int j = 0; j < 4; j++)
      for (int r = 0; r < 4; r++) {
        float p = __expf(sc[j][r] - m_i[r]);
        sc[j][r] = p;
        psum[r] += p;
      }
    for (int off = 1; off < 16; off <<= 1)
      for (int r = 0; r < 4; r++) psum[r] += __shfl_xor(psum[r], off, 64);
    for (int r = 0; r < 4; r++) l_i[r] = l_i[r] * alpha[r] + psum[r];
    for (int i = 0; i < 8; i++)
      for (int r = 0; r < 4; r++) oacc[i][r] *= alpha[r];

    // P: C-layout -> A-layout via per-wave LDS roundtrip (swizzled).
    // write: element (row=quad*4+r, col=j*16+l16) -> data chunk j*2+(l16>>3),
    // stored at chunk ^ (row&7), in-chunk pos l16&7.
    for (int j = 0; j < 4; j++)
      for (int r = 0; r < 4; r++) {
        int qr = quad * 4 + r;
        sP[wave][qr * 64 + (((j * 2 + (l16 >> 3)) ^ (qr & 7)) * 8) + (l16 & 7)]
            = f2bf(sc[j][r]);
      }
    asm volatile("s_waitcnt lgkmcnt(0)" ::: "memory");
    bf16x8 pa[2];
    for (int c = 0; c < 2; c++)
      pa[c] = *(const bf16x8*)(&sP[wave][l16 * 64
                                         + (((c * 4 + quad) ^ (l16 & 7)) * 8)]);
    // P V   (row = ds*16+l16)
    for (int ds = 0; ds < 8; ds++)
      for (int c = 0; c < 2; c++) {
        bf16x8 vb = *(const bf16x8*)(&sVT[(ds * 16 + l16) * 64
                                          + (((c * 4 + quad) ^ (l16 & 7)) * 8)]);
        oacc[ds] = __builtin_amdgcn_mfma_f32_16x16x32_bf16(pa[c], vb, oacc[ds], 0, 0, 0);
      }
  }
  for (int r = 0; r < 4; r++) {
    float inv = 1.0f / l_i[r];
    size_t rowo = ((size_t)(b * SEQ + qb + quad * 4 + r)) * DMODEL + h * HDIM;
    for (int ds = 0; ds < 8; ds++)
      obuf[rowo + ds * 16 + l16] = f2bf(oacc[ds][r] * inv);
  }
}

// ------------------------------------------------------------------------
extern "C" void kernel_launch(void* const* d_in, const int* in_sizes, int n_in,
                              void* d_out, int out_size, void* d_ws, size_t ws_size,
                              hipStream_t stream) {
  const float* x     = (const float*)d_in[0];
  const float* wq_k  = (const float*)d_in[2];
  const float* wq_b  = (const float*)d_in[3];
  const float* wk_k  = (const float*)d_in[4];
  const float* wk_b  = (const float*)d_in[5];
  const float* wv_k  = (const float*)d_in[6];
  const float* wv_b  = (const float*)d_in[7];
  const float* wo_k  = (const float*)d_in[8];
  const float* wo_b  = (const float*)d_in[9];
  const float* w1_k  = (const float*)d_in[10];
  const float* w1_b  = (const float*)d_in[11];
  const float* w2_k  = (const float*)d_in[12];
  const float* w2_b  = (const float*)d_in[13];
  const float* ln1_s = (const float*)d_in[14];
  const float* ln1_b = (const float*)d_in[15];
  const float* ln2_s = (const float*)d_in[16];
  const float* ln2_b = (const float*)d_in[17];

  // workspace layout (bytes, all 256-aligned); total ~188 MB
  char* ws = (char*)d_ws;
  float*    xres = (float*)(ws + 0);                //  33.55 MB f32 [4096][2048]
  ushort_t* hbuf = (ushort_t*)(ws + 33554432);      //  16.78 MB bf16 [4096][2048]
  ushort_t* wt   = (ushort_t*)(ws + 50331648);      //  33.55 MB bf16 weight scratch
  ushort_t* qkv  = (ushort_t*)(ws + 83886080);      //  18.87 MB bf16 [4096][2304]
  ushort_t* obuf = (ushort_t*)(ws + 102760448);     //  16.78 MB bf16 [4096][2048]
  ushort_t* vt   = (ushort_t*)(ws + 119537664);     //   1.05 MB bf16 [2][128][2048]
  float*    bq   = (float*)(ws + 120586240);        //   9 KB  f32 [2304]
  ushort_t* ffb  = (ushort_t*)(ws + 120595456);     //  67.11 MB bf16 [4096][8192]
  if (ws_size < (size_t)187704320) return;

  dim3 t256(256), t512(512), t32x8(32, 8);

  // LN1
  ln_kernel<<<4096, t256, 0, stream>>>(x, ln1_s, ln1_b, hbuf);
  // fused QKV weights -> bf16 [2304][2048] transposed, plus bias concat
  concat_bias<<<9, t256, 0, stream>>>(wq_b, wk_b, wv_b, bq);
  transpose_convert<<<dim3(64, 64), t32x8, 0, stream>>>(wq_k, wt, 2048, 2048);
  transpose_convert<<<dim3(4, 64), t32x8, 0, stream>>>(wk_k, wt + (size_t)2048 * 2048, 2048, 128);
  transpose_convert<<<dim3(4, 64), t32x8, 0, stream>>>(wv_k, wt + (size_t)2176 * 2048, 2048, 128);
  // QKV projection (N = 2304): 18x32 = 576 blocks, 128^2 tiles
  gemm_bt<0><<<576, t256, 0, stream>>>(hbuf, wt, qkv, bq, nullptr, QKVN, 2048, 18);
  // V transpose for attention's PV operand
  transpose_v<<<dim3(64, 4, 2), t32x8, 0, stream>>>(qkv, vt);
  // attention
  flash_kernel<<<dim3(32, 16, 2), t256, 0, stream>>>(qkv, vt, obuf);
  // out-proj + residual -> xres (f32): 16x32 = 512 blocks, 128^2 tiles
  transpose_convert<<<dim3(64, 64), t32x8, 0, stream>>>(wo_k, wt, 2048, 2048);
  gemm_bt<1><<<512, t256, 0, stream>>>(obuf, wt, xres, wo_b, x, 2048, 2048, 16);
  // LN2
  ln_kernel<<<4096, t256, 0, stream>>>(xres, ln2_s, ln2_b, hbuf);
  // FFN1 + exact GELU -> ffb (bf16): 32x16 = 512 blocks, 256^2 8-phase
  transpose_convert<<<dim3(256, 64), t32x8, 0, stream>>>(w1_k, wt, 2048, 8192);
  gemm_bt_8p<2><<<512, t512, 0, stream>>>(hbuf, wt, ffb, w1_b, nullptr, 8192, 2048, 32);
  // FFN2 + residual -> d_out (f32): 16x32 = 512 blocks, 128^2 tiles
  transpose_convert<<<dim3(64, 256), t32x8, 0, stream>>>(w2_k, wt, 8192, 2048);
  gemm_bt<1><<<512, t256, 0, stream>>>(ffb, wt, (float*)d_out, w2_b, xres, 2048, 8192, 16);
}

// Round 4
// 958.061 us; speedup vs baseline: 2.6017x; 1.0120x over previous
//
#include <hip/hip_runtime.h>
#include <math.h>

typedef unsigned short ushort_t;
typedef __bf16 bf16x8 __attribute__((ext_vector_type(8)));
typedef float f32x4 __attribute__((ext_vector_type(4)));

#define SEQ 2048
#define DMODEL 2048
#define NBATCH 2
#define NHEAD 16
#define HDIM 128
#define FFDIM 8192
#define QKVN 2304   // 2048 (Q) + 128 (K) + 128 (V)

typedef __attribute__((address_space(1))) void as1_void;
typedef __attribute__((address_space(3))) void as3_void;

__device__ __forceinline__ void async_cp16(const void* g, void* l) {
  __builtin_amdgcn_global_load_lds((as1_void*)(void*)g, (as3_void*)l, 16, 0, 0);
}

__device__ __forceinline__ ushort_t f2bf(float f) {
  unsigned u = __float_as_uint(f);
  u += 0x7fff + ((u >> 16) & 1);   // round-to-nearest-even
  return (ushort_t)(u >> 16);
}

// raw HW barrier + compiler memory fence (NO sched_barrier: m141 showed
// order-pinning defeats the compiler's own scheduling, ~510-600 TF cap)
__device__ __forceinline__ void block_bar() {
  asm volatile("" ::: "memory");
  __builtin_amdgcn_s_barrier();
  asm volatile("" ::: "memory");
}

#define S_VMCNT(n) asm volatile("s_waitcnt vmcnt(" #n ")" ::: "memory")

// ---------------- LayerNorm: f32 in -> bf16 out -------------------------
__global__ __launch_bounds__(256) void ln_kernel(const float* __restrict__ x,
    const float* __restrict__ gamma, const float* __restrict__ beta,
    ushort_t* __restrict__ out) {
  int row = blockIdx.x;
  int tid = threadIdx.x;
  const float4* xr = (const float4*)(x + (size_t)row * DMODEL);
  float4 a = xr[tid];
  float4 b = xr[256 + tid];
  float s  = a.x + a.y + a.z + a.w + b.x + b.y + b.z + b.w;
  float ss = a.x*a.x + a.y*a.y + a.z*a.z + a.w*a.w
           + b.x*b.x + b.y*b.y + b.z*b.z + b.w*b.w;
  for (int off = 1; off < 64; off <<= 1) {
    s  += __shfl_xor(s,  off, 64);
    ss += __shfl_xor(ss, off, 64);
  }
  __shared__ float red[8];
  int wave = tid >> 6, lane = tid & 63;
  if (lane == 0) { red[wave] = s; red[4 + wave] = ss; }
  __syncthreads();
  s  = red[0] + red[1] + red[2] + red[3];
  ss = red[4] + red[5] + red[6] + red[7];
  float mean = s * (1.0f / DMODEL);
  float var  = ss * (1.0f / DMODEL) - mean * mean;
  float rs   = rsqrtf(var + 1e-5f);
  const float4* g4 = (const float4*)gamma;
  const float4* b4 = (const float4*)beta;
  float4 g0 = g4[tid], g1 = g4[256 + tid];
  float4 e0 = b4[tid], e1 = b4[256 + tid];
  ushort_t* o = out + (size_t)row * DMODEL;
  ushort4 p0, p1;
  p0.x = f2bf((a.x - mean) * rs * g0.x + e0.x);
  p0.y = f2bf((a.y - mean) * rs * g0.y + e0.y);
  p0.z = f2bf((a.z - mean) * rs * g0.z + e0.z);
  p0.w = f2bf((a.w - mean) * rs * g0.w + e0.w);
  p1.x = f2bf((b.x - mean) * rs * g1.x + e1.x);
  p1.y = f2bf((b.y - mean) * rs * g1.y + e1.y);
  p1.z = f2bf((b.z - mean) * rs * g1.z + e1.z);
  p1.w = f2bf((b.w - mean) * rs * g1.w + e1.w);
  ((ushort4*)o)[tid]       = p0;
  ((ushort4*)o)[256 + tid] = p1;
}

// ------------- transpose + f32->bf16: src[Ks][Ns] -> dst[Ns][Ks] --------
__global__ __launch_bounds__(256) void transpose_convert(
    const float* __restrict__ src, ushort_t* __restrict__ dst, int Ks, int Ns) {
  __shared__ float tile[32][33];
  int nb = blockIdx.x * 32, kb = blockIdx.y * 32;
  int tx = threadIdx.x, ty = threadIdx.y;   // (32,8)
  for (int i = 0; i < 4; i++) {
    int k = kb + ty * 4 + i;
    tile[ty * 4 + i][tx] = src[(size_t)k * Ns + nb + tx];
  }
  __syncthreads();
  for (int i = 0; i < 4; i++) {
    int n = nb + ty * 4 + i;
    dst[(size_t)n * Ks + kb + tx] = f2bf(tile[tx][ty * 4 + i]);
  }
}

// ------------- V slice of qkv -> transposed vt[b][d][s] (bf16) ----------
__global__ __launch_bounds__(256) void transpose_v(
    const ushort_t* __restrict__ qkv, ushort_t* __restrict__ vt) {
  __shared__ ushort_t tile[32][33];
  int sb = blockIdx.x * 32, db = blockIdx.y * 32, b = blockIdx.z;
  int tx = threadIdx.x, ty = threadIdx.y;
  for (int i = 0; i < 4; i++) {
    int s = sb + ty * 4 + i;
    tile[ty * 4 + i][tx] = qkv[((size_t)(b * SEQ + s)) * QKVN + 2176 + db + tx];
  }
  __syncthreads();
  for (int i = 0; i < 4; i++) {
    int d = db + ty * 4 + i;
    vt[((size_t)(b * HDIM + d)) * SEQ + sb + tx] = tile[tx][ty * 4 + i];
  }
}

// ------------- concat q/k/v biases into one [2304] vector ---------------
__global__ void concat_bias(const float* __restrict__ qb, const float* __restrict__ kb,
                            const float* __restrict__ vb, float* __restrict__ dst) {
  int i = blockIdx.x * 256 + threadIdx.x;
  if (i < 2048) dst[i] = qb[i];
  else if (i < 2176) dst[i] = kb[i - 2048];
  else if (i < 2304) dst[i] = vb[i - 2176];
}

// ------------- GEMM 128x128 (r0 structure) + XCD-chunked swizzle --------
// MODE 0: bf16 out = acc + bias ; MODE 1: f32 out = resid + acc + bias ;
// MODE 2: bf16 out = gelu(acc + bias)
template <int MODE>
__global__ __launch_bounds__(256) void gemm_bt(const ushort_t* __restrict__ A,
    const ushort_t* __restrict__ Bt, void* __restrict__ Cv,
    const float* __restrict__ bias, const float* __restrict__ resid,
    int N, int K, int GN) {
  __shared__ ushort_t sA[2][128 * 32];
  __shared__ ushort_t sB[2][128 * 32];
  int nwg = gridDim.x;
  int wg = blockIdx.x;
  int swz = (wg & 7) * (nwg >> 3) + (wg >> 3);
  int bm = swz / GN, bn = swz % GN;
  int tid = threadIdx.x, wave = tid >> 6, lane = tid & 63;
  int quad = lane >> 4, l16 = lane & 15;
  int wm = wave >> 1, wn = wave & 1;
  f32x4 acc[4][4];
  for (int i = 0; i < 4; i++)
    for (int j = 0; j < 4; j++) { f32x4 z = {0.f, 0.f, 0.f, 0.f}; acc[i][j] = z; }
  const ushort_t* Ab = A + (size_t)(bm * 128) * K;
  const ushort_t* Bb = Bt + (size_t)(bn * 128) * K;
  int cb = wave * 128;
  int c0 = cb + lane;
  size_t arow = (size_t)(c0 >> 2) * K + (c0 & 3) * 8;
  size_t arow1 = (size_t)((c0 + 64) >> 2) * K + ((c0 + 64) & 3) * 8;
  int nk = K >> 5;
  async_cp16(Ab + arow, &sA[0][cb * 8]);
  async_cp16(Ab + arow1, &sA[0][(cb + 64) * 8]);
  async_cp16(Bb + arow, &sB[0][cb * 8]);
  async_cp16(Bb + arow1, &sB[0][(cb + 64) * 8]);
  for (int ki = 0; ki < nk; ki++) {
    int cur = ki & 1;
    __syncthreads();
    if (ki + 1 < nk) {
      int k0 = (ki + 1) << 5;
      async_cp16(Ab + arow + k0, &sA[cur ^ 1][cb * 8]);
      async_cp16(Ab + arow1 + k0, &sA[cur ^ 1][(cb + 64) * 8]);
      async_cp16(Bb + arow + k0, &sB[cur ^ 1][cb * 8]);
      async_cp16(Bb + arow1 + k0, &sB[cur ^ 1][(cb + 64) * 8]);
    }
    bf16x8 af[4], bf[4];
    for (int i = 0; i < 4; i++)
      af[i] = *(const bf16x8*)(&sA[cur][(wm * 64 + i * 16 + l16) * 32 + quad * 8]);
    for (int j = 0; j < 4; j++)
      bf[j] = *(const bf16x8*)(&sB[cur][(wn * 64 + j * 16 + l16) * 32 + quad * 8]);
    for (int i = 0; i < 4; i++)
      for (int j = 0; j < 4; j++)
        acc[i][j] = __builtin_amdgcn_mfma_f32_16x16x32_bf16(af[i], bf[j], acc[i][j], 0, 0, 0);
  }
  for (int i = 0; i < 4; i++) {
    for (int r = 0; r < 4; r++) {
      size_t row = (size_t)(bm * 128 + wm * 64 + i * 16 + quad * 4 + r);
      for (int j = 0; j < 4; j++) {
        int col = bn * 128 + wn * 64 + j * 16 + l16;
        float v = acc[i][j][r] + bias[col];
        size_t idx = row * (size_t)N + col;
        if (MODE == 0) {
          ((ushort_t*)Cv)[idx] = f2bf(v);
        } else if (MODE == 1) {
          ((float*)Cv)[idx] = resid[idx] + v;
        } else {
          float g = 0.5f * v * (1.0f + erff(v * 0.70710678118654752f));
          ((ushort_t*)Cv)[idx] = f2bf(g);
        }
      }
    }
  }
}

// ---- 8-phase 256x256 GEMM (T2+T3+T4+T5), for large-N GEMMs (FFN1) ------
// LDS XOR swizzle: data chunk qd of row r lives at chunk r*4 + (qd ^ ((r>>1)&3)).
// Read rows are always wbase + i*16 + l16 (wbase, i*16 multiples of 16), so
// (r>>1)&3 == (l16>>1)&3 -- a per-lane CONSTANT. All fragment addresses are
// base(buf,ks) + laneoff + i*1024B with compile-time i-offsets (hoisted).
template <int MODE>
__global__ __launch_bounds__(512) void gemm_bt_8p(const ushort_t* __restrict__ A,
    const ushort_t* __restrict__ Bt, void* __restrict__ Cv,
    const float* __restrict__ bias, const float* __restrict__ resid,
    int N, int K, int GN) {
  __shared__ ushort_t sA[2][2][256 * 32];
  __shared__ ushort_t sB[2][2][256 * 32];
  int nwg = gridDim.x;
  int wg = blockIdx.x;
  int swz = (wg & 7) * (nwg >> 3) + (wg >> 3);
  int bm = swz / GN, bn = swz % GN;
  int tid = threadIdx.x, wave = tid >> 6, lane = tid & 63;
  int quad = lane >> 4, l16 = lane & 15;
  int wm = wave >> 2, wn = wave & 3;
  f32x4 acc[8][4];
  for (int i = 0; i < 8; i++)
    for (int j = 0; j < 4; j++) { f32x4 z = {0.f, 0.f, 0.f, 0.f}; acc[i][j] = z; }
  const ushort_t* Ab = A  + (size_t)(bm * 256) * K;
  const ushort_t* Bb = Bt + (size_t)(bn * 256) * K;
  int ca = wave * 64 + lane;
  int cb2 = 512 + wave * 64 + lane;
  int ra = ca >> 2,  qa = (ca & 3)  ^ ((ra >> 1) & 3);
  int rb = cb2 >> 2, qb2 = (cb2 & 3) ^ ((rb >> 1) & 3);
  size_t off0 = (size_t)ra * K + qa * 8;
  size_t off1 = (size_t)rb * K + qb2 * 8;
  int lb0 = (wave * 64) * 8;
  int lb1 = (512 + wave * 64) * 8;
  // hoisted per-lane read offsets (in ushorts): XOR term is lane-constant
  int Q8  = (quad ^ ((l16 >> 1) & 3)) * 8;
  int offA = (wm * 128 + l16) * 32 + Q8;
  int offB = (wn * 64  + l16) * 32 + Q8;
#define STG8(SS, Xb, bb, ks, kk) do { \
    async_cp16((Xb) + off0 + (size_t)((kk) + (ks) * 32), &SS[bb][ks][lb0]); \
    async_cp16((Xb) + off1 + (size_t)((kk) + (ks) * 32), &SS[bb][ks][lb1]); \
  } while (0)

  int NT = K >> 6;
  STG8(sA, Ab, 0, 0, 0);
  STG8(sB, Bb, 0, 0, 0);
  STG8(sA, Ab, 0, 1, 0);
  STG8(sB, Bb, 0, 1, 0);
  S_VMCNT(4);
  block_bar();

  bf16x8 a[4], b[4];
  for (int t = 0; t < NT; t++) {
    int cur = t & 1, nxt = cur ^ 1;
    bool more = (t + 1 < NT);
    int kk = (t + 1) << 6;
    const ushort_t* A0 = &sA[cur][0][offA];
    const ushort_t* B0 = &sB[cur][0][offB];
    const ushort_t* A1 = &sA[cur][1][offA];
    const ushort_t* B1 = &sB[cur][1][offB];
    // ---------------- phase 1 (i0-3, k0) ----------------
    for (int i = 0; i < 4; i++) a[i] = *(const bf16x8*)(A0 + i * 512);
    for (int j = 0; j < 4; j++) b[j] = *(const bf16x8*)(B0 + j * 512);
    if (more) STG8(sA, Ab, nxt, 0, kk);
    block_bar();
    __builtin_amdgcn_s_setprio(1);
    for (int i = 0; i < 4; i++)
      for (int j = 0; j < 4; j++)
        acc[i][j] = __builtin_amdgcn_mfma_f32_16x16x32_bf16(a[i], b[j], acc[i][j], 0, 0, 0);
    __builtin_amdgcn_s_setprio(0);
    block_bar();
    // ---------------- phase 2 (i4-7, k0) ----------------
    for (int i = 0; i < 4; i++) a[i] = *(const bf16x8*)(A0 + 2048 + i * 512);
    if (more) STG8(sB, Bb, nxt, 0, kk);
    block_bar();
    __builtin_amdgcn_s_setprio(1);
    for (int i = 0; i < 4; i++)
      for (int j = 0; j < 4; j++)
        acc[4 + i][j] = __builtin_amdgcn_mfma_f32_16x16x32_bf16(a[i], b[j], acc[4 + i][j], 0, 0, 0);
    __builtin_amdgcn_s_setprio(0);
    if (more) { S_VMCNT(4); } else { S_VMCNT(0); }
    block_bar();
    // ---------------- phase 3 (i0-3, k1) ----------------
    for (int i = 0; i < 4; i++) a[i] = *(const bf16x8*)(A1 + i * 512);
    for (int j = 0; j < 4; j++) b[j] = *(const bf16x8*)(B1 + j * 512);
    if (more) STG8(sA, Ab, nxt, 1, kk);
    block_bar();
    __builtin_amdgcn_s_setprio(1);
    for (int i = 0; i < 4; i++)
      for (int j = 0; j < 4; j++)
        acc[i][j] = __builtin_amdgcn_mfma_f32_16x16x32_bf16(a[i], b[j], acc[i][j], 0, 0, 0);
    __builtin_amdgcn_s_setprio(0);
    block_bar();
    // ---------------- phase 4 (i4-7, k1) ----------------
    for (int i = 0; i < 4; i++) a[i] = *(const bf16x8*)(A1 + 2048 + i * 512);
    if (more) STG8(sB, Bb, nxt, 1, kk);
    block_bar();
    __builtin_amdgcn_s_setprio(1);
    for (int i = 0; i < 4; i++)
      for (int j = 0; j < 4; j++)
        acc[4 + i][j] = __builtin_amdgcn_mfma_f32_16x16x32_bf16(a[i], b[j], acc[4 + i][j], 0, 0, 0);
    __builtin_amdgcn_s_setprio(0);
    if (more) { S_VMCNT(4); }
    block_bar();
  }
#undef STG8
  for (int i = 0; i < 8; i++) {
    for (int r = 0; r < 4; r++) {
      size_t row = (size_t)(bm * 256 + wm * 128 + i * 16 + quad * 4 + r);
      for (int j = 0; j < 4; j++) {
        int col = bn * 256 + wn * 64 + j * 16 + l16;
        float v = acc[i][j][r] + bias[col];
        size_t idx = row * (size_t)N + col;
        if (MODE == 0) {
          ((ushort_t*)Cv)[idx] = f2bf(v);
        } else if (MODE == 1) {
          ((float*)Cv)[idx] = resid[idx] + v;
        } else {
          float g = 0.5f * v * (1.0f + erff(v * 0.70710678118654752f));
          ((ushort_t*)Cv)[idx] = f2bf(g);
        }
      }
    }
  }
}

// ------------- Flash attention (causal, MQA) ----------------------------
// grid (S/64, H, B), block 256 = 4 waves; wave owns 16 q-rows.
// LDS XOR-swizzle (T2 / G4, both-sides per rule #21).
__global__ __launch_bounds__(256) void flash_kernel(const ushort_t* __restrict__ qkv,
    const ushort_t* __restrict__ vt, ushort_t* __restrict__ obuf) {
  __shared__ ushort_t sK[64 * 128];    // K tile  [64 keys][16 chunks] swizzled
  __shared__ ushort_t sVT[128 * 64];   // V^T tile [128 d][8 chunks] swizzled
  __shared__ ushort_t sP[4][16 * 64];  // per-wave P relayout buffer, swizzled
  int qt = blockIdx.x, h = blockIdx.y, b = blockIdx.z;
  int tid = threadIdx.x, wave = tid >> 6, lane = tid & 63;
  int quad = lane >> 4, l16 = lane & 15;
  int qb = qt * 64 + wave * 16;
  size_t batch_off = (size_t)b * SEQ * QKVN;

  bf16x8 aq[4];
  {
    const ushort_t* qp = qkv + batch_off + (size_t)(qb + l16) * QKVN + h * HDIM + quad * 8;
    for (int c = 0; c < 4; c++) aq[c] = *(const bf16x8*)(qp + c * 32);
  }
  f32x4 oacc[8];
  for (int i = 0; i < 8; i++) { f32x4 z = {0.f, 0.f, 0.f, 0.f}; oacc[i] = z; }
  float m_i[4], l_i[4];
  for (int r = 0; r < 4; r++) { m_i[r] = -1e30f; l_i[r] = 0.f; }
  const float scale = 0.08838834764831845f;  // 1/sqrt(128)

  for (int kt = 0; kt <= qt; kt++) {
    __syncthreads();   // previous iteration done with sK/sVT
    for (int t = 0; t < 4; t++) {
      int cb = wave * 256 + t * 64;
      int c  = cb + lane;
      // sK dest chunk c = (row=c>>4, st=c&15); source data chunk = st ^ (row&7)
      async_cp16(qkv + batch_off + (size_t)(kt * 64 + (c >> 4)) * QKVN + 2048
                     + (size_t)(((c & 15) ^ ((c >> 4) & 7)) * 8),
                 &sK[cb * 8]);
      // sVT dest chunk c = (row=c>>3, st=c&7); source data chunk = st ^ (row&7)
      async_cp16(vt + ((size_t)(b * HDIM + (c >> 3))) * SEQ + kt * 64
                    + (size_t)(((c & 7) ^ ((c >> 3) & 7)) * 8),
                 &sVT[cb * 8]);
    }
    __syncthreads();   // staged (compiler drains vmcnt before barrier)

    // Q K^T  (row = j*16+l16; data chunk c*4+quad read at chunk^(row&7))
    f32x4 sc[4];
    for (int j = 0; j < 4; j++) {
      f32x4 z = {0.f, 0.f, 0.f, 0.f};
      for (int c = 0; c < 4; c++) {
        bf16x8 bk = *(const bf16x8*)(&sK[(j * 16 + l16) * 128
                                         + (((c * 4 + quad) ^ (l16 & 7)) * 8)]);
        z = __builtin_amdgcn_mfma_f32_16x16x32_bf16(aq[c], bk, z, 0, 0, 0);
      }
      sc[j] = z;
    }
    // scale + causal mask + online softmax
    float rmax[4] = {-1e30f, -1e30f, -1e30f, -1e30f};
    for (int j = 0; j < 4; j++) {
      int col = kt * 64 + j * 16 + l16;
      for (int r = 0; r < 4; r++) {
        int rowg = qb + quad * 4 + r;
        float v = (col <= rowg) ? sc[j][r] * scale : -1e30f;
        sc[j][r] = v;
        rmax[r] = fmaxf(rmax[r], v);
      }
    }
    for (int off = 1; off < 16; off <<= 1)
      for (int r = 0; r < 4; r++) rmax[r] = fmaxf(rmax[r], __shfl_xor(rmax[r], off, 64));
    float alpha[4], psum[4];
    for (int r = 0; r < 4; r++) {
      float mn = fmaxf(m_i[r], rmax[r]);
      alpha[r] = __expf(m_i[r] - mn);
      m_i[r] = mn;
      psum[r] = 0.f;
    }
    for (int j = 0; j < 4; j++)
      for (int r = 0; r < 4; r++) {
        float p = __expf(sc[j][r] - m_i[r]);
        sc[j][r] = p;
        psum[r] += p;
      }
    for (int off = 1; off < 16; off <<= 1)
      for (int r = 0; r < 4; r++) psum[r] += __shfl_xor(psum[r], off, 64);
    for (int r = 0; r < 4; r++) l_i[r] = l_i[r] * alpha[r] + psum[r];
    for (int i = 0; i < 8; i++)
      for (int r = 0; r < 4; r++) oacc[i][r] *= alpha[r];

    // P: C-layout -> A-layout via per-wave LDS roundtrip (swizzled).
    for (int j = 0; j < 4; j++)
      for (int r = 0; r < 4; r++) {
        int qr = quad * 4 + r;
        sP[wave][qr * 64 + (((j * 2 + (l16 >> 3)) ^ (qr & 7)) * 8) + (l16 & 7)]
            = f2bf(sc[j][r]);
      }
    asm volatile("s_waitcnt lgkmcnt(0)" ::: "memory");
    bf16x8 pa[2];
    for (int c = 0; c < 2; c++)
      pa[c] = *(const bf16x8*)(&sP[wave][l16 * 64
                                         + (((c * 4 + quad) ^ (l16 & 7)) * 8)]);
    // P V   (row = ds*16+l16)
    for (int ds = 0; ds < 8; ds++)
      for (int c = 0; c < 2; c++) {
        bf16x8 vb = *(const bf16x8*)(&sVT[(ds * 16 + l16) * 64
                                          + (((c * 4 + quad) ^ (l16 & 7)) * 8)]);
        oacc[ds] = __builtin_amdgcn_mfma_f32_16x16x32_bf16(pa[c], vb, oacc[ds], 0, 0, 0);
      }
  }
  for (int r = 0; r < 4; r++) {
    float inv = 1.0f / l_i[r];
    size_t rowo = ((size_t)(b * SEQ + qb + quad * 4 + r)) * DMODEL + h * HDIM;
    for (int ds = 0; ds < 8; ds++)
      obuf[rowo + ds * 16 + l16] = f2bf(oacc[ds][r] * inv);
  }
}

// ------------------------------------------------------------------------
extern "C" void kernel_launch(void* const* d_in, const int* in_sizes, int n_in,
                              void* d_out, int out_size, void* d_ws, size_t ws_size,
                              hipStream_t stream) {
  const float* x     = (const float*)d_in[0];
  const float* wq_k  = (const float*)d_in[2];
  const float* wq_b  = (const float*)d_in[3];
  const float* wk_k  = (const float*)d_in[4];
  const float* wk_b  = (const float*)d_in[5];
  const float* wv_k  = (const float*)d_in[6];
  const float* wv_b  = (const float*)d_in[7];
  const float* wo_k  = (const float*)d_in[8];
  const float* wo_b  = (const float*)d_in[9];
  const float* w1_k  = (const float*)d_in[10];
  const float* w1_b  = (const float*)d_in[11];
  const float* w2_k  = (const float*)d_in[12];
  const float* w2_b  = (const float*)d_in[13];
  const float* ln1_s = (const float*)d_in[14];
  const float* ln1_b = (const float*)d_in[15];
  const float* ln2_s = (const float*)d_in[16];
  const float* ln2_b = (const float*)d_in[17];

  // workspace layout (bytes, all 256-aligned); total ~188 MB
  char* ws = (char*)d_ws;
  float*    xres = (float*)(ws + 0);                //  33.55 MB f32 [4096][2048]
  ushort_t* hbuf = (ushort_t*)(ws + 33554432);      //  16.78 MB bf16 [4096][2048]
  ushort_t* wt   = (ushort_t*)(ws + 50331648);      //  33.55 MB bf16 weight scratch
  ushort_t* qkv  = (ushort_t*)(ws + 83886080);      //  18.87 MB bf16 [4096][2304]
  ushort_t* obuf = (ushort_t*)(ws + 102760448);     //  16.78 MB bf16 [4096][2048]
  ushort_t* vt   = (ushort_t*)(ws + 119537664);     //   1.05 MB bf16 [2][128][2048]
  float*    bq   = (float*)(ws + 120586240);        //   9 KB  f32 [2304]
  ushort_t* ffb  = (ushort_t*)(ws + 120595456);     //  67.11 MB bf16 [4096][8192]
  if (ws_size < (size_t)187704320) return;

  dim3 t256(256), t512(512), t32x8(32, 8);

  // LN1
  ln_kernel<<<4096, t256, 0, stream>>>(x, ln1_s, ln1_b, hbuf);
  // fused QKV weights -> bf16 [2304][2048] transposed, plus bias concat
  concat_bias<<<9, t256, 0, stream>>>(wq_b, wk_b, wv_b, bq);
  transpose_convert<<<dim3(64, 64), t32x8, 0, stream>>>(wq_k, wt, 2048, 2048);
  transpose_convert<<<dim3(4, 64), t32x8, 0, stream>>>(wk_k, wt + (size_t)2048 * 2048, 2048, 128);
  transpose_convert<<<dim3(4, 64), t32x8, 0, stream>>>(wv_k, wt + (size_t)2176 * 2048, 2048, 128);
  // QKV projection (N = 2304): 18x32 = 576 blocks, 128^2 tiles
  gemm_bt<0><<<576, t256, 0, stream>>>(hbuf, wt, qkv, bq, nullptr, QKVN, 2048, 18);
  // V transpose for attention's PV operand
  transpose_v<<<dim3(64, 4, 2), t32x8, 0, stream>>>(qkv, vt);
  // attention
  flash_kernel<<<dim3(32, 16, 2), t256, 0, stream>>>(qkv, vt, obuf);
  // out-proj + residual -> xres (f32): 16x32 = 512 blocks, 128^2 tiles
  transpose_convert<<<dim3(64, 64), t32x8, 0, stream>>>(wo_k, wt, 2048, 2048);
  gemm_bt<1><<<512, t256, 0, stream>>>(obuf, wt, xres, wo_b, x, 2048, 2048, 16);
  // LN2
  ln_kernel<<<4096, t256, 0, stream>>>(xres, ln2_s, ln2_b, hbuf);
  // FFN1 + exact GELU -> ffb (bf16): 32x16 = 512 blocks, 256^2 8-phase
  transpose_convert<<<dim3(256, 64), t32x8, 0, stream>>>(w1_k, wt, 2048, 8192);
  gemm_bt_8p<2><<<512, t512, 0, stream>>>(hbuf, wt, ffb, w1_b, nullptr, 8192, 2048, 32);
  // FFN2 + residual -> d_out (f32): 16x32 = 512 blocks, 128^2 tiles
  transpose_convert<<<dim3(64, 256), t32x8, 0, stream>>>(w2_k, wt, 8192, 2048);
  gemm_bt<1><<<512, t256, 0, stream>>>(ffb, wt, (float*)d_out, w2_b, xres, 2048, 8192, 16);
}